// Round 11
// baseline (282.136 us; speedup 1.0000x reference)
//
#include <hip/hip_runtime.h>
#include <hip/hip_bf16.h>
#include <math.h>

#define NN     50000
#define FIN    128
#define F1     64      // H1*C1 = layer-1 output features
#define NH1    8
#define F2     64      // layer-2 output features

#define BSH    256                         // nodes per dst bucket (CSR build)
#define NB     ((NN + BSH - 1) / BSH)      // 196 buckets
#define BCAP   9472                        // per-bucket edge cap (mean 8448, +11 sigma)

typedef __bf16 bf16x8 __attribute__((ext_vector_type(8)));
typedef float  f32x4  __attribute__((ext_vector_type(4)));

// ---------------- runtime dtype helpers ----------------
// flags[0] = 1 if float tensors are fp32 (else bf16)
// flags[1] = 1 if edge_index is int64 (else int32)

__device__ __forceinline__ float loadF(const void* p, long long i, int fp32) {
    if (fp32) return ((const float*)p)[i];
    return __bfloat162float(((const __hip_bfloat16*)p)[i]);
}
__device__ __forceinline__ int loadI_nt(const void* p, long long i, int i64) {
    if (i64) return (int)__builtin_nontemporal_load(&((const long long*)p)[i]);
    return __builtin_nontemporal_load(&((const int*)p)[i]);
}
__device__ __forceinline__ unsigned short f2bfu(float f) {   // RNE f32->bf16 bits
    unsigned u = __float_as_uint(f);
    return (unsigned short)((u + 0x7FFFu + ((u >> 16) & 1u)) >> 16);
}
__device__ __forceinline__ float b2f(unsigned short u) {
    return __uint_as_float(((unsigned)u) << 16);
}

// ---------------- combined sniff + weight pre-swizzle (1 block) ----------------

__global__ void k_pre(const void* __restrict__ x, const void* __restrict__ ei,
                      int* __restrict__ flags,
                      const void* __restrict__ W1, const void* __restrict__ W2,
                      unsigned short* __restrict__ W1p, unsigned short* __restrict__ W2p) {
    __shared__ int s_nanexp, s_oddnz, s_fp32;
    if (threadIdx.x == 0) { s_nanexp = 0; s_oddnz = 0; }
    __syncthreads();
    const unsigned short* u = (const unsigned short*)x;
    int cnt = 0;
    for (int i = threadIdx.x; i < 8192; i += 256) {
        unsigned short v = u[i];
        if ((v & 0x7F80) == 0x7F80) cnt++;         // bf16 Inf/NaN bit pattern
    }
    if (cnt) atomicAdd(&s_nanexp, cnt);
    const unsigned* e32 = (const unsigned*)ei;
    int nz = 0;
    for (int i = threadIdx.x; i < 2048; i += 256) {
        if (e32[2 * i + 1] != 0u) nz++;            // high words if int64
    }
    if (nz) atomicAdd(&s_oddnz, nz);
    __syncthreads();
    if (threadIdx.x == 0) {
        s_fp32 = (s_nanexp > 2) ? 1 : 0;
        flags[0] = s_fp32;
        flags[1] = (s_oddnz == 0) ? 1 : 0;
    }
    __syncthreads();
    int fp32 = s_fp32;
    for (int i = threadIdx.x; i < (FIN / 32) * 4 * 512; i += 256) {   // 8192
        int j = i & 7, l = (i >> 3) & 63, f = i >> 9;
        int kb = f >> 2, nt = f & 3;
        int k = kb * 32 + (l >> 4) * 8 + j, n = nt * 16 + (l & 15);
        W1p[i] = f2bfu(loadF(W1, k * 64 + n, fp32));
    }
    for (int i = threadIdx.x; i < (F1 / 32) * 4 * 512; i += 256) {    // 4096
        int j = i & 7, l = (i >> 3) & 63, f = i >> 9;
        int kb = f >> 2, nt = f & 3;
        int k = kb * 32 + (l >> 4) * 8 + j, n = nt * 16 + (l & 15);
        W2p[i] = f2bfu(loadF(W2, k * 64 + n, fp32));
    }
}

// ---------------- CSR build: bucket bin + per-block LDS counting sort ----
// 2048 edges/block (806 blocks) — R10's 403 blocks was only 1.6/CU.

__global__ __launch_bounds__(256) void k_bin_fine(
    const void* __restrict__ ei, int E, int Etot,
    int* __restrict__ bcnt, unsigned* __restrict__ binned,
    const int* __restrict__ flags) {
    int i64 = flags[1];
    __shared__ int hist[NB], gbase[NB];
    for (int i = threadIdx.x; i < NB; i += 256) hist[i] = 0;
    __syncthreads();
    long long base = (long long)blockIdx.x * 2048;
    unsigned pk[8]; short bb[8];
    #pragma unroll
    for (int u = 0; u < 8; ++u) {
        long long j = base + u * 256 + threadIdx.x;
        int s = -1, d = -1;
        if (j < Etot) {
            if (j < E) { s = loadI_nt(ei, j, i64); d = loadI_nt(ei, (long long)E + j, i64); }
            else       { s = d = (int)(j - E); }
        }
        if ((unsigned)s < NN && (unsigned)d < NN) {
            bb[u] = (short)(d >> 8);
            pk[u] = ((unsigned)s << 8) | (unsigned)(d & 255);
            atomicAdd(&hist[bb[u]], 1);
        } else bb[u] = -1;
    }
    __syncthreads();
    for (int i = threadIdx.x; i < NB; i += 256) {
        int h = hist[i];
        gbase[i] = h ? atomicAdd(&bcnt[i], h) : 0;
        hist[i] = 0;                                 // reuse as local cursor
    }
    __syncthreads();
    #pragma unroll
    for (int u = 0; u < 8; ++u) {
        if (bb[u] >= 0) {
            int pos = gbase[bb[u]] + atomicAdd(&hist[bb[u]], 1);
            if (pos < BCAP) binned[(size_t)bb[u] * BCAP + pos] = pk[u];
        }
    }
}

__global__ __launch_bounds__(256) void k_csr_local(
    const int* __restrict__ bcnt, const unsigned* __restrict__ binned,
    int* __restrict__ offs, int* __restrict__ perm) {
    __shared__ int hist[BSH], cur[BSH], sd[BSH];
    int bk = blockIdx.x, tid = threadIdx.x;
    int n0 = bk * BSH;
    // phase 0: prefix over the 196 bucket counts
    int pv = (tid < NB) ? min(bcnt[tid], BCAP) : 0;
    sd[tid] = pv;
    __syncthreads();
    #pragma unroll
    for (int off = 1; off < BSH; off <<= 1) {
        int t = (tid >= off) ? sd[tid - off] : 0;
        __syncthreads();
        sd[tid] += t;
        __syncthreads();
    }
    int gb = (bk > 0) ? sd[bk - 1] : 0;
    if (bk == 0 && tid == 0) offs[NN] = sd[NB - 1];
    __syncthreads();
    // phase 1: histogram of dst&255 within bucket
    int cnt = bcnt[bk]; if (cnt > BCAP) cnt = BCAP;
    const unsigned* bp = binned + (size_t)bk * BCAP;
    hist[tid] = 0;
    __syncthreads();
    for (int i = tid; i < cnt; i += 256)
        atomicAdd(&hist[bp[i] & 255], 1);
    __syncthreads();
    int myh = hist[tid];
    sd[tid] = myh;
    __syncthreads();
    #pragma unroll
    for (int off = 1; off < BSH; off <<= 1) {
        int t = (tid >= off) ? sd[tid - off] : 0;
        __syncthreads();
        sd[tid] += t;
        __syncthreads();
    }
    int excl = sd[tid] - myh;
    cur[tid] = gb + excl;
    if (n0 + tid < NN) offs[n0 + tid] = gb + excl;
    __syncthreads();
    for (int i = tid; i < cnt; i += 256) {
        unsigned pk = bp[i];
        int pos = atomicAdd(&cur[pk & 255], 1);
        perm[pos] = (int)(pk >> 8);
    }
}

// ---------------- MFMA GEMM (layer 1): h1 = x @ W1, + a1s/a1d ----------------

__global__ __launch_bounds__(256) void k_mgemm1(
    const void* __restrict__ x, const unsigned short* __restrict__ W1p,
    const void* __restrict__ attS, const void* __restrict__ attD,
    __hip_bfloat16* __restrict__ h1, _Float16* __restrict__ a1s,
    float* __restrict__ a1d, const int* __restrict__ flags) {
    int fp32 = flags[0];
    __shared__ unsigned short hl[64 * 64];   // 8 KB, bf16 bits
    __shared__ float attSl[64], attDl[64];
    int tid = threadIdx.x;
    if (tid < 64) { attSl[tid] = loadF(attS, tid, fp32); attDl[tid] = loadF(attD, tid, fp32); }
    int w = tid >> 6, l = tid & 63;
    int quad = l >> 4, lm = l & 15;
    int n0 = blockIdx.x * 64;

    bf16x8 bfr[16];
    #pragma unroll
    for (int f = 0; f < 16; ++f)
        bfr[f] = *(const bf16x8*)(W1p + f * 512 + l * 8);

    int nodeA = n0 + w * 16 + lm;
    long long rowA = (nodeA < NN) ? nodeA : 0;     // clamp; garbage unused
    f32x4 acc[4];
    #pragma unroll
    for (int nt = 0; nt < 4; ++nt) acc[nt] = (f32x4){0.f, 0.f, 0.f, 0.f};

    #pragma unroll
    for (int kb = 0; kb < 4; ++kb) {
        bf16x8 af;
        if (!fp32) {
            af = *(const bf16x8*)((const unsigned short*)x + rowA * FIN + kb * 32 + quad * 8);
        } else {
            const float* xf = (const float*)x + rowA * FIN + kb * 32 + quad * 8;
            union { unsigned short s[8]; bf16x8 v; } tmp;
            #pragma unroll
            for (int j = 0; j < 8; ++j) tmp.s[j] = f2bfu(xf[j]);
            af = tmp.v;
        }
        #pragma unroll
        for (int nt = 0; nt < 4; ++nt)
            acc[nt] = __builtin_amdgcn_mfma_f32_16x16x32_bf16(af, bfr[kb * 4 + nt], acc[nt], 0, 0, 0);
    }

    #pragma unroll
    for (int nt = 0; nt < 4; ++nt) {
        #pragma unroll
        for (int r = 0; r < 4; ++r) {
            int nl = w * 16 + quad * 4 + r;
            int node = n0 + nl;
            int c = nt * 16 + lm;
            unsigned short hb = f2bfu(acc[nt][r]);
            hl[nl * 64 + c] = hb;
            if (node < NN) ((unsigned short*)h1)[(size_t)node * 64 + c] = hb;
        }
    }
    __syncthreads();
    // a1s/a1d per (node, head): 64 nodes x 8 heads = 512 pairs
    #pragma unroll
    for (int pp = 0; pp < 2; ++pp) {
        int p = tid + pp * 256;
        int nl = p >> 3, g = p & 7;
        int node = n0 + nl;
        float ss = 0.f, dd = 0.f;
        #pragma unroll
        for (int j = 0; j < 8; ++j) {
            float hv = b2f(hl[nl * 64 + g * 8 + j]);
            ss += hv * attSl[g * 8 + j];
            dd += hv * attDl[g * 8 + j];
        }
        if (node < NN) {
            a1s[(size_t)node * NH1 + g] = (_Float16)ss;
            a1d[(size_t)node * NH1 + g] = dd;
        }
    }
}

// ---------------- MFMA GEMM (layer 2): h2 = helu @ W2, + a2s/a2d ----------------

__global__ __launch_bounds__(256) void k_mgemm2(
    const __hip_bfloat16* __restrict__ helu, const unsigned short* __restrict__ W2p,
    const void* __restrict__ attS, const void* __restrict__ attD,
    __hip_bfloat16* __restrict__ h2, _Float16* __restrict__ a2s,
    float* __restrict__ a2d, const int* __restrict__ flags) {
    int fp32 = flags[0];
    __shared__ unsigned short hl[64 * 64];   // 8 KB
    __shared__ float attSl[64], attDl[64];
    __shared__ float sp[64 * 8], dp[64 * 8];
    int tid = threadIdx.x;
    if (tid < 64) { attSl[tid] = loadF(attS, tid, fp32); attDl[tid] = loadF(attD, tid, fp32); }
    int w = tid >> 6, l = tid & 63;
    int quad = l >> 4, lm = l & 15;
    int n0 = blockIdx.x * 64;

    bf16x8 bfr[8];
    #pragma unroll
    for (int f = 0; f < 8; ++f)
        bfr[f] = *(const bf16x8*)(W2p + f * 512 + l * 8);

    int nodeA = n0 + w * 16 + lm;
    long long rowA = (nodeA < NN) ? nodeA : 0;
    f32x4 acc[4];
    #pragma unroll
    for (int nt = 0; nt < 4; ++nt) acc[nt] = (f32x4){0.f, 0.f, 0.f, 0.f};

    #pragma unroll
    for (int kb = 0; kb < 2; ++kb) {
        bf16x8 af = *(const bf16x8*)((const unsigned short*)helu + rowA * F1 + kb * 32 + quad * 8);
        #pragma unroll
        for (int nt = 0; nt < 4; ++nt)
            acc[nt] = __builtin_amdgcn_mfma_f32_16x16x32_bf16(af, bfr[kb * 4 + nt], acc[nt], 0, 0, 0);
    }

    #pragma unroll
    for (int nt = 0; nt < 4; ++nt) {
        #pragma unroll
        for (int r = 0; r < 4; ++r) {
            int nl = w * 16 + quad * 4 + r;
            int node = n0 + nl;
            int c = nt * 16 + lm;
            unsigned short hb = f2bfu(acc[nt][r]);
            hl[nl * 64 + c] = hb;
            if (node < NN) ((unsigned short*)h2)[(size_t)node * 64 + c] = hb;
        }
    }
    __syncthreads();
    #pragma unroll
    for (int pp = 0; pp < 2; ++pp) {
        int p = tid + pp * 256;
        int nl = p >> 3, g = p & 7;
        float ss = 0.f, dd = 0.f;
        #pragma unroll
        for (int j = 0; j < 8; ++j) {
            float hv = b2f(hl[nl * 64 + g * 8 + j]);
            ss += hv * attSl[g * 8 + j];
            dd += hv * attDl[g * 8 + j];
        }
        sp[nl * 8 + g] = ss;
        dp[nl * 8 + g] = dd;
    }
    __syncthreads();
    if (tid < 64) {
        int node = n0 + tid;
        if (node < NN) {
            float ss = 0.f, dd = 0.f;
            #pragma unroll
            for (int g = 0; g < 8; ++g) { ss += sp[tid * 8 + g]; dd += dp[tid * 8 + g]; }
            a2s[node] = (_Float16)ss;
            a2d[node] = dd;
        }
    }
}

// ---------------- Layer 1 aggregation: split-role + pipelined ----------------
// R10 lesson: keep the gather row WAVE-UNIFORM (readlane -> scalar base) —
// divergent row index defeats saddr and costs per-lane 64b address math.
// Phase A: lane (u=c&7, h=c>>3) computes p(edge u, head h) once; commit is
// 8 uniform-row ushort gathers; next batch's perm/a1s prefetched in between.

__global__ __launch_bounds__(256) void k_agg1(
    const int* __restrict__ offs, const int* __restrict__ perm,
    const __hip_bfloat16* __restrict__ h1, const _Float16* __restrict__ a1s,
    const float* __restrict__ a1d, const void* __restrict__ b1,
    __hip_bfloat16* __restrict__ helu, int n, const int* __restrict__ flags) {
    int fp32 = flags[0];
    int w = threadIdx.x >> 6, c = threadIdx.x & 63;
    int d = blockIdx.x * 4 + w;
    if (d >= n) return;
    int start = offs[d], end = offs[d + 1];
    int u = c & 7, h = c >> 3, cb = c & 56;
    float adl = a1d[(size_t)d * NH1 + h];
    const unsigned short* hu = (const unsigned short*)h1;
    float acc = 0.f, denp = 0.f;

    int j0 = start + u;
    int sj = perm[(j0 < end) ? j0 : (end - 1)];
    float as = (float)a1s[(size_t)sj * NH1 + h];

    for (int ib = start; ib < end; ib += 8) {
        float e = as + adl;
        e = fmaxf(e, 0.2f * e);                      // leaky_relu(0.2)
        float p = (ib + u < end) ? __expf(e) : 0.f;
        denp += p;
        // prefetch next batch (uniform-safe)
        int sjn = sj; float asn = as;
        if (ib + 8 < end) {
            int jn = ib + 8 + u;
            sjn = perm[(jn < end) ? jn : (end - 1)];
            asn = (float)a1s[(size_t)sjn * NH1 + h];
        }
        #pragma unroll
        for (int k = 0; k < 8; ++k) {
            int su = __builtin_amdgcn_readlane(sj, k);           // wave-uniform src
            float pk = __shfl(p, cb + k, 64);                    // p(edge k, my head)
            acc = fmaf(pk, b2f(hu[(size_t)su * 64 + c]), acc);
        }
        sj = sjn; as = asn;
    }
    denp += __shfl_xor(denp, 1, 64);
    denp += __shfl_xor(denp, 2, 64);
    denp += __shfl_xor(denp, 4, 64);                 // den for head c>>3
    float v = acc / (denp + 1e-16f) + loadF(b1, c, fp32);
    v = (v > 0.f) ? v : expm1f(v);                   // ELU
    helu[(size_t)d * 64 + c] = __float2bfloat16(v);
}

// ---------------- Layer 2 aggregation + final linear (uniform + pipelined) ----------------

__global__ __launch_bounds__(256) void k_agg2(
    const int* __restrict__ offs, const int* __restrict__ perm,
    const __hip_bfloat16* __restrict__ h2, const _Float16* __restrict__ a2s,
    const float* __restrict__ a2d, const void* __restrict__ b2,
    const void* __restrict__ linW, const void* __restrict__ linb,
    void* __restrict__ out, int n, const int* __restrict__ flags) {
    int fp32 = flags[0];
    int w = threadIdx.x >> 6, c = threadIdx.x & 63;
    int d = blockIdx.x * 4 + w;
    if (d >= n) return;
    int start = offs[d], end = offs[d + 1];
    int u = c & 7;
    float ad = a2d[d];
    const unsigned short* hu = (const unsigned short*)h2;
    float acc = 0.f, denp = 0.f;

    int j0 = start + u;
    int sj = perm[(j0 < end) ? j0 : (end - 1)];
    float as = (float)a2s[sj];

    for (int ib = start; ib < end; ib += 8) {
        float e = as + ad;
        e = fmaxf(e, 0.2f * e);
        float p = (ib + u < end) ? __expf(e) : 0.f;
        denp += (c < 8) ? p : 0.f;                   // dedup (p duplicated across groups)
        int sjn = sj; float asn = as;
        if (ib + 8 < end) {
            int jn = ib + 8 + u;
            sjn = perm[(jn < end) ? jn : (end - 1)];
            asn = (float)a2s[sjn];
        }
        #pragma unroll
        for (int k = 0; k < 8; ++k) {
            int su = __builtin_amdgcn_readlane(sj, k);
            float pk = __uint_as_float(__builtin_amdgcn_readlane(__float_as_uint(p), k));
            acc = fmaf(pk, b2f(hu[(size_t)su * 64 + c]), acc);
        }
        sj = sjn; as = asn;
    }
    #pragma unroll
    for (int off = 1; off < 64; off <<= 1) denp += __shfl_xor(denp, off, 64);
    float v = acc / (denp + 1e-16f) + loadF(b2, c, fp32);
    float part = v * loadF(linW, c, fp32);
    #pragma unroll
    for (int off = 1; off < 64; off <<= 1) part += __shfl_xor(part, off, 64);
    if (c == 0) {
        float r = part + loadF(linb, 0, fp32);
        if (fp32) ((float*)out)[d] = r;
        else      ((__hip_bfloat16*)out)[d] = __float2bfloat16(r);
    }
}

// ---------------- host launcher ----------------

static inline char* carve(char*& p, size_t bytes) {
    char* r = p;
    p += (bytes + 255) & ~size_t(255);
    return r;
}

extern "C" void kernel_launch(void* const* d_in, const int* in_sizes, int n_in,
                              void* d_out, int out_size, void* d_ws, size_t ws_size,
                              hipStream_t stream) {
    const void* x     = d_in[0];
    const void* ei    = d_in[1];
    const void* W1    = d_in[2];
    const void* attS1 = d_in[3];
    const void* attD1 = d_in[4];
    const void* b1    = d_in[5];
    const void* W2    = d_in[6];
    const void* attS2 = d_in[7];
    const void* attD2 = d_in[8];
    const void* b2    = d_in[9];
    const void* linW  = d_in[10];
    const void* linb  = d_in[11];

    int E    = in_sizes[1] / 2;
    int Etot = E + NN;

    // workspace layout (~22 MB)
    char* p = (char*)d_ws;
    int*   flags = (int*)carve(p, 256);
    int*   bcnt  = (int*)carve(p, (size_t)NB * 4);
    unsigned short* W1p = (unsigned short*)carve(p, 8192 * 2);
    unsigned short* W2p = (unsigned short*)carve(p, 4096 * 2);
    int*   offs  = (int*)carve(p, (size_t)(NN + 1) * 4);       // 200 KB
    int*   perm  = (int*)carve(p, (size_t)Etot * 4);           // 6.6 MB
    // big region: binned (7.43 MB) dead after k_csr_local, then aliased by
    // a1s f16 (0.8) + a1d f32 (1.6) + h1 (6.4) written by k_mgemm1 afterwards.
    char*  big   = carve(p, 8800000);
    unsigned* binned = (unsigned*)big;
    _Float16* a1s    = (_Float16*)big;                           // 0.8 MB
    float*    a1d    = (float*)(big + 800000);                   // 1.6 MB
    __hip_bfloat16* h1   = (__hip_bfloat16*)(big + 2400000);     // 6.4 MB
    __hip_bfloat16* helu = (__hip_bfloat16*)carve(p, (size_t)NN * F1 * 2); // 6.4 MB
    _Float16* a2s = a1s;
    float*    a2d = a1d;
    __hip_bfloat16* h2 = h1;

    hipMemsetAsync(bcnt, 0, (size_t)NB * 4, stream);
    k_pre<<<1, 256, 0, stream>>>(x, ei, flags, W1, W2, W1p, W2p);

    int ab = (Etot + 2047) / 2048;
    k_bin_fine<<<ab, 256, 0, stream>>>(ei, E, Etot, bcnt, binned, flags);
    k_csr_local<<<NB, 256, 0, stream>>>(bcnt, binned, offs, perm);

    int ng = (NN + 63) / 64;
    k_mgemm1<<<ng, 256, 0, stream>>>(x, W1p, attS1, attD1, h1, a1s, a1d, flags);
    k_agg1<<<(NN + 3) / 4, 256, 0, stream>>>(offs, perm, h1, a1s, a1d, b1, helu, NN, flags);
    k_mgemm2<<<ng, 256, 0, stream>>>(helu, W2p, attS2, attD2, h2, a2s, a2d, flags);
    k_agg2<<<(NN + 3) / 4, 256, 0, stream>>>(offs, perm, h2, a2s, a2d, b2, linW, linb, d_out, NN, flags);
}

// Round 12
// 255.000 us; speedup vs baseline: 1.1064x; 1.1064x over previous
//
#include <hip/hip_runtime.h>
#include <hip/hip_bf16.h>
#include <math.h>

#define NN     50000
#define FIN    128
#define F1     64      // H1*C1 = layer-1 output features
#define NH1    8
#define F2     64      // layer-2 output features

#define BSH    256                         // nodes per dst bucket (CSR build)
#define NB     ((NN + BSH - 1) / BSH)      // 196 buckets
#define BCAP   9472                        // per-bucket edge cap (mean 8448, +11 sigma)

typedef __bf16 bf16x8 __attribute__((ext_vector_type(8)));
typedef float  f32x4  __attribute__((ext_vector_type(4)));

// ---------------- runtime dtype helpers ----------------
// flags[0] = 1 if float tensors are fp32 (else bf16)
// flags[1] = 1 if edge_index is int64 (else int32)

__device__ __forceinline__ float loadF(const void* p, long long i, int fp32) {
    if (fp32) return ((const float*)p)[i];
    return __bfloat162float(((const __hip_bfloat16*)p)[i]);
}
__device__ __forceinline__ int loadI_nt(const void* p, long long i, int i64) {
    if (i64) return (int)__builtin_nontemporal_load(&((const long long*)p)[i]);
    return __builtin_nontemporal_load(&((const int*)p)[i]);
}
__device__ __forceinline__ unsigned short f2bfu(float f) {   // RNE f32->bf16 bits
    unsigned u = __float_as_uint(f);
    return (unsigned short)((u + 0x7FFFu + ((u >> 16) & 1u)) >> 16);
}
__device__ __forceinline__ float b2f(unsigned short u) {
    return __uint_as_float(((unsigned)u) << 16);
}

// ---------------- sniff + weight pre-swizzle (multi-block) ----------------
// R11 lesson: single-block k_pre serializes ~12k conversions on one CU at the
// head of the dependency chain. Now 49 blocks: each redundantly sniffs dtype
// flags from a sample (L2-served, cheap) and swizzles its 1/49 slice.

#define PREB 49

__global__ __launch_bounds__(256) void k_pre(
    const void* __restrict__ x, const void* __restrict__ ei,
    int* __restrict__ flags,
    const void* __restrict__ W1, const void* __restrict__ W2,
    unsigned short* __restrict__ W1p, unsigned short* __restrict__ W2p) {
    __shared__ int s_nanexp, s_oddnz, s_fp32;
    if (threadIdx.x == 0) { s_nanexp = 0; s_oddnz = 0; }
    __syncthreads();
    const unsigned short* u = (const unsigned short*)x;
    int cnt = 0;
    for (int i = threadIdx.x; i < 8192; i += 256) {
        unsigned short v = u[i];
        if ((v & 0x7F80) == 0x7F80) cnt++;         // bf16 Inf/NaN bit pattern
    }
    if (cnt) atomicAdd(&s_nanexp, cnt);
    const unsigned* e32 = (const unsigned*)ei;
    int nz = 0;
    for (int i = threadIdx.x; i < 2048; i += 256) {
        if (e32[2 * i + 1] != 0u) nz++;            // high words if int64
    }
    if (nz) atomicAdd(&s_oddnz, nz);
    __syncthreads();
    if (threadIdx.x == 0) {
        s_fp32 = (s_nanexp > 2) ? 1 : 0;
        if (blockIdx.x == 0) {
            flags[0] = s_fp32;
            flags[1] = (s_oddnz == 0) ? 1 : 0;
        }
    }
    __syncthreads();
    int fp32 = s_fp32;
    int gt = blockIdx.x * 256 + threadIdx.x, gs = PREB * 256;
    for (int i = gt; i < (FIN / 32) * 4 * 512; i += gs) {   // 8192
        int j = i & 7, l = (i >> 3) & 63, f = i >> 9;
        int kb = f >> 2, nt = f & 3;
        int k = kb * 32 + (l >> 4) * 8 + j, n = nt * 16 + (l & 15);
        W1p[i] = f2bfu(loadF(W1, k * 64 + n, fp32));
    }
    for (int i = gt; i < (F1 / 32) * 4 * 512; i += gs) {    // 4096
        int j = i & 7, l = (i >> 3) & 63, f = i >> 9;
        int kb = f >> 2, nt = f & 3;
        int k = kb * 32 + (l >> 4) * 8 + j, n = nt * 16 + (l & 15);
        W2p[i] = f2bfu(loadF(W2, k * 64 + n, fp32));
    }
}

// ---------------- CSR build: bucket bin + per-block LDS counting sort ----

__global__ __launch_bounds__(256) void k_bin_fine(
    const void* __restrict__ ei, int E, int Etot,
    int* __restrict__ bcnt, unsigned* __restrict__ binned,
    const int* __restrict__ flags) {
    int i64 = flags[1];
    __shared__ int hist[NB], gbase[NB];
    for (int i = threadIdx.x; i < NB; i += 256) hist[i] = 0;
    __syncthreads();
    long long base = (long long)blockIdx.x * 2048;
    unsigned pk[8]; short bb[8];
    #pragma unroll
    for (int u = 0; u < 8; ++u) {
        long long j = base + u * 256 + threadIdx.x;
        int s = -1, d = -1;
        if (j < Etot) {
            if (j < E) { s = loadI_nt(ei, j, i64); d = loadI_nt(ei, (long long)E + j, i64); }
            else       { s = d = (int)(j - E); }
        }
        if ((unsigned)s < NN && (unsigned)d < NN) {
            bb[u] = (short)(d >> 8);
            pk[u] = ((unsigned)s << 8) | (unsigned)(d & 255);
            atomicAdd(&hist[bb[u]], 1);
        } else bb[u] = -1;
    }
    __syncthreads();
    for (int i = threadIdx.x; i < NB; i += 256) {
        int h = hist[i];
        gbase[i] = h ? atomicAdd(&bcnt[i], h) : 0;
        hist[i] = 0;                                 // reuse as local cursor
    }
    __syncthreads();
    #pragma unroll
    for (int u = 0; u < 8; ++u) {
        if (bb[u] >= 0) {
            int pos = gbase[bb[u]] + atomicAdd(&hist[bb[u]], 1);
            if (pos < BCAP) binned[(size_t)bb[u] * BCAP + pos] = pk[u];
        }
    }
}

__global__ __launch_bounds__(256) void k_csr_local(
    const int* __restrict__ bcnt, const unsigned* __restrict__ binned,
    int* __restrict__ offs, int* __restrict__ perm) {
    __shared__ int hist[BSH], cur[BSH], sd[BSH];
    int bk = blockIdx.x, tid = threadIdx.x;
    int n0 = bk * BSH;
    // phase 0: prefix over the 196 bucket counts
    int pv = (tid < NB) ? min(bcnt[tid], BCAP) : 0;
    sd[tid] = pv;
    __syncthreads();
    #pragma unroll
    for (int off = 1; off < BSH; off <<= 1) {
        int t = (tid >= off) ? sd[tid - off] : 0;
        __syncthreads();
        sd[tid] += t;
        __syncthreads();
    }
    int gb = (bk > 0) ? sd[bk - 1] : 0;
    if (bk == 0 && tid == 0) offs[NN] = sd[NB - 1];
    __syncthreads();
    // phase 1: histogram of dst&255 within bucket
    int cnt = bcnt[bk]; if (cnt > BCAP) cnt = BCAP;
    const unsigned* bp = binned + (size_t)bk * BCAP;
    hist[tid] = 0;
    __syncthreads();
    for (int i = tid; i < cnt; i += 256)
        atomicAdd(&hist[bp[i] & 255], 1);
    __syncthreads();
    int myh = hist[tid];
    sd[tid] = myh;
    __syncthreads();
    #pragma unroll
    for (int off = 1; off < BSH; off <<= 1) {
        int t = (tid >= off) ? sd[tid - off] : 0;
        __syncthreads();
        sd[tid] += t;
        __syncthreads();
    }
    int excl = sd[tid] - myh;
    cur[tid] = gb + excl;
    if (n0 + tid < NN) offs[n0 + tid] = gb + excl;
    __syncthreads();
    for (int i = tid; i < cnt; i += 256) {
        unsigned pk = bp[i];
        int pos = atomicAdd(&cur[pk & 255], 1);
        perm[pos] = (int)(pk >> 8);
    }
}

// ---------------- MFMA GEMM (layer 1): h1 = x @ W1, + a1s/a1d (R9 exact) ----------------

__global__ __launch_bounds__(256) void k_mgemm1(
    const void* __restrict__ x, const unsigned short* __restrict__ W1p,
    const void* __restrict__ attS, const void* __restrict__ attD,
    __hip_bfloat16* __restrict__ h1, float* __restrict__ a1s,
    float* __restrict__ a1d, const int* __restrict__ flags) {
    int fp32 = flags[0];
    __shared__ unsigned short hl[64 * 64];   // 8 KB, bf16 bits
    __shared__ float attSl[64], attDl[64];
    int tid = threadIdx.x;
    if (tid < 64) { attSl[tid] = loadF(attS, tid, fp32); attDl[tid] = loadF(attD, tid, fp32); }
    int w = tid >> 6, l = tid & 63;
    int quad = l >> 4, lm = l & 15;
    int n0 = blockIdx.x * 64;

    bf16x8 bfr[16];
    #pragma unroll
    for (int f = 0; f < 16; ++f)
        bfr[f] = *(const bf16x8*)(W1p + f * 512 + l * 8);

    int nodeA = n0 + w * 16 + lm;
    long long rowA = (nodeA < NN) ? nodeA : 0;     // clamp; garbage unused
    f32x4 acc[4];
    #pragma unroll
    for (int nt = 0; nt < 4; ++nt) acc[nt] = (f32x4){0.f, 0.f, 0.f, 0.f};

    #pragma unroll
    for (int kb = 0; kb < 4; ++kb) {
        bf16x8 af;
        if (!fp32) {
            af = *(const bf16x8*)((const unsigned short*)x + rowA * FIN + kb * 32 + quad * 8);
        } else {
            const float* xf = (const float*)x + rowA * FIN + kb * 32 + quad * 8;
            union { unsigned short s[8]; bf16x8 v; } tmp;
            #pragma unroll
            for (int j = 0; j < 8; ++j) tmp.s[j] = f2bfu(xf[j]);
            af = tmp.v;
        }
        #pragma unroll
        for (int nt = 0; nt < 4; ++nt)
            acc[nt] = __builtin_amdgcn_mfma_f32_16x16x32_bf16(af, bfr[kb * 4 + nt], acc[nt], 0, 0, 0);
    }

    #pragma unroll
    for (int nt = 0; nt < 4; ++nt) {
        #pragma unroll
        for (int r = 0; r < 4; ++r) {
            int nl = w * 16 + quad * 4 + r;
            int node = n0 + nl;
            int c = nt * 16 + lm;
            unsigned short hb = f2bfu(acc[nt][r]);
            hl[nl * 64 + c] = hb;
            if (node < NN) ((unsigned short*)h1)[(size_t)node * 64 + c] = hb;
        }
    }
    __syncthreads();
    // a1s/a1d per (node, head): 64 nodes x 8 heads = 512 pairs
    #pragma unroll
    for (int pp = 0; pp < 2; ++pp) {
        int p = tid + pp * 256;
        int nl = p >> 3, g = p & 7;
        int node = n0 + nl;
        float ss = 0.f, dd = 0.f;
        #pragma unroll
        for (int j = 0; j < 8; ++j) {
            float hv = b2f(hl[nl * 64 + g * 8 + j]);
            ss += hv * attSl[g * 8 + j];
            dd += hv * attDl[g * 8 + j];
        }
        if (node < NN) {
            a1s[(size_t)node * NH1 + g] = ss;
            a1d[(size_t)node * NH1 + g] = dd;
        }
    }
}

// ---------------- MFMA GEMM (layer 2): h2 = helu @ W2, + a2s/a2d (R9 exact) ----------------

__global__ __launch_bounds__(256) void k_mgemm2(
    const __hip_bfloat16* __restrict__ helu, const unsigned short* __restrict__ W2p,
    const void* __restrict__ attS, const void* __restrict__ attD,
    __hip_bfloat16* __restrict__ h2, float* __restrict__ a2s,
    float* __restrict__ a2d, const int* __restrict__ flags) {
    int fp32 = flags[0];
    __shared__ unsigned short hl[64 * 64];   // 8 KB
    __shared__ float attSl[64], attDl[64];
    __shared__ float sp[64 * 8], dp[64 * 8];
    int tid = threadIdx.x;
    if (tid < 64) { attSl[tid] = loadF(attS, tid, fp32); attDl[tid] = loadF(attD, tid, fp32); }
    int w = tid >> 6, l = tid & 63;
    int quad = l >> 4, lm = l & 15;
    int n0 = blockIdx.x * 64;

    bf16x8 bfr[8];
    #pragma unroll
    for (int f = 0; f < 8; ++f)
        bfr[f] = *(const bf16x8*)(W2p + f * 512 + l * 8);

    int nodeA = n0 + w * 16 + lm;
    long long rowA = (nodeA < NN) ? nodeA : 0;
    f32x4 acc[4];
    #pragma unroll
    for (int nt = 0; nt < 4; ++nt) acc[nt] = (f32x4){0.f, 0.f, 0.f, 0.f};

    #pragma unroll
    for (int kb = 0; kb < 2; ++kb) {
        bf16x8 af = *(const bf16x8*)((const unsigned short*)helu + rowA * F1 + kb * 32 + quad * 8);
        #pragma unroll
        for (int nt = 0; nt < 4; ++nt)
            acc[nt] = __builtin_amdgcn_mfma_f32_16x16x32_bf16(af, bfr[kb * 4 + nt], acc[nt], 0, 0, 0);
    }

    #pragma unroll
    for (int nt = 0; nt < 4; ++nt) {
        #pragma unroll
        for (int r = 0; r < 4; ++r) {
            int nl = w * 16 + quad * 4 + r;
            int node = n0 + nl;
            int c = nt * 16 + lm;
            unsigned short hb = f2bfu(acc[nt][r]);
            hl[nl * 64 + c] = hb;
            if (node < NN) ((unsigned short*)h2)[(size_t)node * 64 + c] = hb;
        }
    }
    __syncthreads();
    #pragma unroll
    for (int pp = 0; pp < 2; ++pp) {
        int p = tid + pp * 256;
        int nl = p >> 3, g = p & 7;
        float ss = 0.f, dd = 0.f;
        #pragma unroll
        for (int j = 0; j < 8; ++j) {
            float hv = b2f(hl[nl * 64 + g * 8 + j]);
            ss += hv * attSl[g * 8 + j];
            dd += hv * attDl[g * 8 + j];
        }
        sp[nl * 8 + g] = ss;
        dp[nl * 8 + g] = dd;
    }
    __syncthreads();
    if (tid < 64) {
        int node = n0 + tid;
        if (node < NN) {
            float ss = 0.f, dd = 0.f;
            #pragma unroll
            for (int g = 0; g < 8; ++g) { ss += sp[tid * 8 + g]; dd += dp[tid * 8 + g]; }
            a2s[node] = ss;
            a2d[node] = dd;
        }
    }
}

// ---------------- Layer 1 aggregation (R9 exact — measured optimum) ----------------
// R10 (dword-pairing) and R11 (f16 coefs + manual prefetch) both regressed;
// the compiler pipelines this form best. Keep gather rows wave-uniform.

__global__ __launch_bounds__(256) void k_agg1(
    const int* __restrict__ offs, const int* __restrict__ perm,
    const __hip_bfloat16* __restrict__ h1, const float* __restrict__ a1s,
    const float* __restrict__ a1d, const void* __restrict__ b1,
    __hip_bfloat16* __restrict__ helu, int n, const int* __restrict__ flags) {
    int fp32 = flags[0];
    int w = threadIdx.x >> 6, c = threadIdx.x & 63;
    int d = blockIdx.x * 4 + w;
    if (d >= n) return;
    int start = offs[d], end = offs[d + 1];
    int u = c & 7, h = c >> 3, cb = c & 56;
    float adl = a1d[(size_t)d * NH1 + h];
    const unsigned short* hu = (const unsigned short*)h1;
    float acc = 0.f, denp = 0.f;
    for (int i = start; i < end; i += 8) {
        int j = i + u;
        int jc = (j < end) ? j : (end - 1);
        int sj = perm[jc];
        float e = a1s[(size_t)sj * NH1 + h] + adl;
        e = fmaxf(e, 0.2f * e);                      // leaky_relu(0.2)
        float p = (j < end) ? __expf(e) : 0.f;
        denp += p;
        #pragma unroll
        for (int k = 0; k < 8; ++k) {
            int su = __builtin_amdgcn_readlane(sj, k);           // wave-uniform src
            float pk = __shfl(p, cb + k, 64);                    // p(edge k, my head)
            acc = fmaf(pk, b2f(hu[(size_t)su * 64 + c]), acc);
        }
    }
    denp += __shfl_xor(denp, 1, 64);
    denp += __shfl_xor(denp, 2, 64);
    denp += __shfl_xor(denp, 4, 64);                 // den for head c>>3
    float v = acc / (denp + 1e-16f) + loadF(b1, c, fp32);
    v = (v > 0.f) ? v : expm1f(v);                   // ELU
    helu[(size_t)d * 64 + c] = __float2bfloat16(v);
}

// ---------------- Layer 2 aggregation + final linear (R9 exact) ----------------

__global__ __launch_bounds__(256) void k_agg2(
    const int* __restrict__ offs, const int* __restrict__ perm,
    const __hip_bfloat16* __restrict__ h2, const float* __restrict__ a2s,
    const float* __restrict__ a2d, const void* __restrict__ b2,
    const void* __restrict__ linW, const void* __restrict__ linb,
    void* __restrict__ out, int n, const int* __restrict__ flags) {
    int fp32 = flags[0];
    int w = threadIdx.x >> 6, c = threadIdx.x & 63;
    int d = blockIdx.x * 4 + w;
    if (d >= n) return;
    int start = offs[d], end = offs[d + 1];
    int u = c & 7;
    float ad = a2d[d];
    const unsigned short* hu = (const unsigned short*)h2;
    float acc = 0.f, denp = 0.f;
    for (int i = start; i < end; i += 8) {
        int j = i + u;
        int jc = (j < end) ? j : (end - 1);
        int sj = perm[jc];
        float e = a2s[sj] + ad;
        e = fmaxf(e, 0.2f * e);
        float p = (j < end) ? __expf(e) : 0.f;
        denp += (c < 8) ? p : 0.f;                   // dedup (p duplicated across groups)
        #pragma unroll
        for (int k = 0; k < 8; ++k) {
            int su = __builtin_amdgcn_readlane(sj, k);
            float pk = __uint_as_float(__builtin_amdgcn_readlane(__float_as_uint(p), k));
            acc = fmaf(pk, b2f(hu[(size_t)su * 64 + c]), acc);
        }
    }
    #pragma unroll
    for (int off = 1; off < 64; off <<= 1) denp += __shfl_xor(denp, off, 64);
    float v = acc / (denp + 1e-16f) + loadF(b2, c, fp32);
    float part = v * loadF(linW, c, fp32);
    #pragma unroll
    for (int off = 1; off < 64; off <<= 1) part += __shfl_xor(part, off, 64);
    if (c == 0) {
        float r = part + loadF(linb, 0, fp32);
        if (fp32) ((float*)out)[d] = r;
        else      ((__hip_bfloat16*)out)[d] = __float2bfloat16(r);
    }
}

// ---------------- host launcher ----------------

static inline char* carve(char*& p, size_t bytes) {
    char* r = p;
    p += (bytes + 255) & ~size_t(255);
    return r;
}

extern "C" void kernel_launch(void* const* d_in, const int* in_sizes, int n_in,
                              void* d_out, int out_size, void* d_ws, size_t ws_size,
                              hipStream_t stream) {
    const void* x     = d_in[0];
    const void* ei    = d_in[1];
    const void* W1    = d_in[2];
    const void* attS1 = d_in[3];
    const void* attD1 = d_in[4];
    const void* b1    = d_in[5];
    const void* W2    = d_in[6];
    const void* attS2 = d_in[7];
    const void* attD2 = d_in[8];
    const void* b2    = d_in[9];
    const void* linW  = d_in[10];
    const void* linb  = d_in[11];

    int E    = in_sizes[1] / 2;
    int Etot = E + NN;

    // workspace layout (~23 MB, R9 layout)
    char* p = (char*)d_ws;
    int*   flags = (int*)carve(p, 256);
    int*   bcnt  = (int*)carve(p, (size_t)NB * 4);
    unsigned short* W1p = (unsigned short*)carve(p, 8192 * 2);
    unsigned short* W2p = (unsigned short*)carve(p, 4096 * 2);
    int*   offs  = (int*)carve(p, (size_t)(NN + 1) * 4);       // 200 KB
    int*   perm  = (int*)carve(p, (size_t)Etot * 4);           // 6.6 MB
    // big region: binned (7.43 MB) dead after k_csr_local, then aliased by
    // a1s (1.6) + a1d (1.6) + h1 (6.4) written by k_mgemm1 afterwards.
    char*  big   = carve(p, 9600000);
    unsigned* binned = (unsigned*)big;
    float*    a1s    = (float*)big;
    float*    a1d    = (float*)(big + 1600000);
    __hip_bfloat16* h1   = (__hip_bfloat16*)(big + 3200000);
    __hip_bfloat16* helu = (__hip_bfloat16*)carve(p, (size_t)NN * F1 * 2); // 6.4 MB
    float* a2s = a1s;
    float* a2d = a1d;
    __hip_bfloat16* h2 = h1;

    hipMemsetAsync(bcnt, 0, (size_t)NB * 4, stream);
    k_pre<<<PREB, 256, 0, stream>>>(x, ei, flags, W1, W2, W1p, W2p);

    int ab = (Etot + 2047) / 2048;
    k_bin_fine<<<ab, 256, 0, stream>>>(ei, E, Etot, bcnt, binned, flags);
    k_csr_local<<<NB, 256, 0, stream>>>(bcnt, binned, offs, perm);

    int ng = (NN + 63) / 64;
    k_mgemm1<<<ng, 256, 0, stream>>>(x, W1p, attS1, attD1, h1, a1s, a1d, flags);
    k_agg1<<<(NN + 3) / 4, 256, 0, stream>>>(offs, perm, h1, a1s, a1d, b1, helu, NN, flags);
    k_mgemm2<<<ng, 256, 0, stream>>>(helu, W2p, attS2, attD2, h2, a2s, a2d, flags);
    k_agg2<<<(NN + 3) / 4, 256, 0, stream>>>(offs, perm, h2, a2s, a2d, b2, linW, linb, d_out, NN, flags);
}

// Round 13
// 251.622 us; speedup vs baseline: 1.1213x; 1.0134x over previous
//
#include <hip/hip_runtime.h>
#include <hip/hip_bf16.h>
#include <math.h>

#define NN     50000
#define FIN    128
#define F1     64      // H1*C1 = layer-1 output features
#define NH1    8
#define F2     64      // layer-2 output features

#define BSH    256                         // nodes per dst bucket (CSR build)
#define NB     ((NN + BSH - 1) / BSH)      // 196 buckets
#define BCAP   9472                        // per-bucket edge cap (mean 8448, +11 sigma)

typedef __bf16 bf16x8 __attribute__((ext_vector_type(8)));
typedef float  f32x4  __attribute__((ext_vector_type(4)));

// ---------------- runtime dtype helpers ----------------
// flags[0] = 1 if float tensors are fp32 (else bf16)
// flags[1] = 1 if edge_index is int64 (else int32)

__device__ __forceinline__ float loadF(const void* p, long long i, int fp32) {
    if (fp32) return ((const float*)p)[i];
    return __bfloat162float(((const __hip_bfloat16*)p)[i]);
}
__device__ __forceinline__ int loadI_nt(const void* p, long long i, int i64) {
    if (i64) return (int)__builtin_nontemporal_load(&((const long long*)p)[i]);
    return __builtin_nontemporal_load(&((const int*)p)[i]);
}
__device__ __forceinline__ unsigned short f2bfu(float f) {   // RNE f32->bf16 bits
    unsigned u = __float_as_uint(f);
    return (unsigned short)((u + 0x7FFFu + ((u >> 16) & 1u)) >> 16);
}
__device__ __forceinline__ float b2f(unsigned short u) {
    return __uint_as_float(((unsigned)u) << 16);
}

// ---------------- sniff + weight pre-swizzle (multi-block) + bcnt zero ----------------

#define PREB 49

__global__ __launch_bounds__(256) void k_pre(
    const void* __restrict__ x, const void* __restrict__ ei,
    int* __restrict__ flags,
    const void* __restrict__ W1, const void* __restrict__ W2,
    unsigned short* __restrict__ W1p, unsigned short* __restrict__ W2p,
    int* __restrict__ bcnt) {
    __shared__ int s_nanexp, s_oddnz, s_fp32;
    if (threadIdx.x == 0) { s_nanexp = 0; s_oddnz = 0; }
    if (blockIdx.x == 0 && threadIdx.x < NB) bcnt[threadIdx.x] = 0;   // folded memset
    __syncthreads();
    const unsigned short* u = (const unsigned short*)x;
    int cnt = 0;
    for (int i = threadIdx.x; i < 8192; i += 256) {
        unsigned short v = u[i];
        if ((v & 0x7F80) == 0x7F80) cnt++;         // bf16 Inf/NaN bit pattern
    }
    if (cnt) atomicAdd(&s_nanexp, cnt);
    const unsigned* e32 = (const unsigned*)ei;
    int nz = 0;
    for (int i = threadIdx.x; i < 2048; i += 256) {
        if (e32[2 * i + 1] != 0u) nz++;            // high words if int64
    }
    if (nz) atomicAdd(&s_oddnz, nz);
    __syncthreads();
    if (threadIdx.x == 0) {
        s_fp32 = (s_nanexp > 2) ? 1 : 0;
        if (blockIdx.x == 0) {
            flags[0] = s_fp32;
            flags[1] = (s_oddnz == 0) ? 1 : 0;
        }
    }
    __syncthreads();
    int fp32 = s_fp32;
    int gt = blockIdx.x * 256 + threadIdx.x, gs = PREB * 256;
    for (int i = gt; i < (FIN / 32) * 4 * 512; i += gs) {   // 8192
        int j = i & 7, l = (i >> 3) & 63, f = i >> 9;
        int kb = f >> 2, nt = f & 3;
        int k = kb * 32 + (l >> 4) * 8 + j, n = nt * 16 + (l & 15);
        W1p[i] = f2bfu(loadF(W1, k * 64 + n, fp32));
    }
    for (int i = gt; i < (F1 / 32) * 4 * 512; i += gs) {    // 4096
        int j = i & 7, l = (i >> 3) & 63, f = i >> 9;
        int kb = f >> 2, nt = f & 3;
        int k = kb * 32 + (l >> 4) * 8 + j, n = nt * 16 + (l & 15);
        W2p[i] = f2bfu(loadF(W2, k * 64 + n, fp32));
    }
}

// ---------------- CSR build: bucket bin + per-block LDS counting sort ----

__global__ __launch_bounds__(256) void k_bin_fine(
    const void* __restrict__ ei, int E, int Etot,
    int* __restrict__ bcnt, unsigned* __restrict__ binned,
    const int* __restrict__ flags) {
    int i64 = flags[1];
    __shared__ int hist[NB], gbase[NB];
    for (int i = threadIdx.x; i < NB; i += 256) hist[i] = 0;
    __syncthreads();
    long long base = (long long)blockIdx.x * 2048;
    unsigned pk[8]; short bb[8];
    #pragma unroll
    for (int u = 0; u < 8; ++u) {
        long long j = base + u * 256 + threadIdx.x;
        int s = -1, d = -1;
        if (j < Etot) {
            if (j < E) { s = loadI_nt(ei, j, i64); d = loadI_nt(ei, (long long)E + j, i64); }
            else       { s = d = (int)(j - E); }
        }
        if ((unsigned)s < NN && (unsigned)d < NN) {
            bb[u] = (short)(d >> 8);
            pk[u] = ((unsigned)s << 8) | (unsigned)(d & 255);
            atomicAdd(&hist[bb[u]], 1);
        } else bb[u] = -1;
    }
    __syncthreads();
    for (int i = threadIdx.x; i < NB; i += 256) {
        int h = hist[i];
        gbase[i] = h ? atomicAdd(&bcnt[i], h) : 0;
        hist[i] = 0;                                 // reuse as local cursor
    }
    __syncthreads();
    #pragma unroll
    for (int u = 0; u < 8; ++u) {
        if (bb[u] >= 0) {
            int pos = gbase[bb[u]] + atomicAdd(&hist[bb[u]], 1);
            if (pos < BCAP) binned[(size_t)bb[u] * BCAP + pos] = pk[u];
        }
    }
}

__global__ __launch_bounds__(256) void k_csr_local(
    const int* __restrict__ bcnt, const unsigned* __restrict__ binned,
    int* __restrict__ offs, int* __restrict__ perm) {
    __shared__ int hist[BSH], cur[BSH], sd[BSH];
    int bk = blockIdx.x, tid = threadIdx.x;
    int n0 = bk * BSH;
    // phase 0: prefix over the 196 bucket counts
    int pv = (tid < NB) ? min(bcnt[tid], BCAP) : 0;
    sd[tid] = pv;
    __syncthreads();
    #pragma unroll
    for (int off = 1; off < BSH; off <<= 1) {
        int t = (tid >= off) ? sd[tid - off] : 0;
        __syncthreads();
        sd[tid] += t;
        __syncthreads();
    }
    int gb = (bk > 0) ? sd[bk - 1] : 0;
    if (bk == 0 && tid == 0) offs[NN] = sd[NB - 1];
    __syncthreads();
    // phase 1: histogram of dst&255 within bucket
    int cnt = bcnt[bk]; if (cnt > BCAP) cnt = BCAP;
    const unsigned* bp = binned + (size_t)bk * BCAP;
    hist[tid] = 0;
    __syncthreads();
    for (int i = tid; i < cnt; i += 256)
        atomicAdd(&hist[bp[i] & 255], 1);
    __syncthreads();
    int myh = hist[tid];
    sd[tid] = myh;
    __syncthreads();
    #pragma unroll
    for (int off = 1; off < BSH; off <<= 1) {
        int t = (tid >= off) ? sd[tid - off] : 0;
        __syncthreads();
        sd[tid] += t;
        __syncthreads();
    }
    int excl = sd[tid] - myh;
    cur[tid] = gb + excl;
    if (n0 + tid < NN) offs[n0 + tid] = gb + excl;
    __syncthreads();
    for (int i = tid; i < cnt; i += 256) {
        unsigned pk = bp[i];
        int pos = atomicAdd(&cur[pk & 255], 1);
        perm[pos] = (int)(pk >> 8);
    }
}

// ---------------- MFMA GEMM (layer 1): h1 = x @ W1, + a1s/a1d (R9 exact) ----------------

__global__ __launch_bounds__(256) void k_mgemm1(
    const void* __restrict__ x, const unsigned short* __restrict__ W1p,
    const void* __restrict__ attS, const void* __restrict__ attD,
    __hip_bfloat16* __restrict__ h1, float* __restrict__ a1s,
    float* __restrict__ a1d, const int* __restrict__ flags) {
    int fp32 = flags[0];
    __shared__ unsigned short hl[64 * 64];   // 8 KB, bf16 bits
    __shared__ float attSl[64], attDl[64];
    int tid = threadIdx.x;
    if (tid < 64) { attSl[tid] = loadF(attS, tid, fp32); attDl[tid] = loadF(attD, tid, fp32); }
    int w = tid >> 6, l = tid & 63;
    int quad = l >> 4, lm = l & 15;
    int n0 = blockIdx.x * 64;

    bf16x8 bfr[16];
    #pragma unroll
    for (int f = 0; f < 16; ++f)
        bfr[f] = *(const bf16x8*)(W1p + f * 512 + l * 8);

    int nodeA = n0 + w * 16 + lm;
    long long rowA = (nodeA < NN) ? nodeA : 0;     // clamp; garbage unused
    f32x4 acc[4];
    #pragma unroll
    for (int nt = 0; nt < 4; ++nt) acc[nt] = (f32x4){0.f, 0.f, 0.f, 0.f};

    #pragma unroll
    for (int kb = 0; kb < 4; ++kb) {
        bf16x8 af;
        if (!fp32) {
            af = *(const bf16x8*)((const unsigned short*)x + rowA * FIN + kb * 32 + quad * 8);
        } else {
            const float* xf = (const float*)x + rowA * FIN + kb * 32 + quad * 8;
            union { unsigned short s[8]; bf16x8 v; } tmp;
            #pragma unroll
            for (int j = 0; j < 8; ++j) tmp.s[j] = f2bfu(xf[j]);
            af = tmp.v;
        }
        #pragma unroll
        for (int nt = 0; nt < 4; ++nt)
            acc[nt] = __builtin_amdgcn_mfma_f32_16x16x32_bf16(af, bfr[kb * 4 + nt], acc[nt], 0, 0, 0);
    }

    #pragma unroll
    for (int nt = 0; nt < 4; ++nt) {
        #pragma unroll
        for (int r = 0; r < 4; ++r) {
            int nl = w * 16 + quad * 4 + r;
            int node = n0 + nl;
            int c = nt * 16 + lm;
            unsigned short hb = f2bfu(acc[nt][r]);
            hl[nl * 64 + c] = hb;
            if (node < NN) ((unsigned short*)h1)[(size_t)node * 64 + c] = hb;
        }
    }
    __syncthreads();
    // a1s/a1d per (node, head): 64 nodes x 8 heads = 512 pairs
    #pragma unroll
    for (int pp = 0; pp < 2; ++pp) {
        int p = tid + pp * 256;
        int nl = p >> 3, g = p & 7;
        int node = n0 + nl;
        float ss = 0.f, dd = 0.f;
        #pragma unroll
        for (int j = 0; j < 8; ++j) {
            float hv = b2f(hl[nl * 64 + g * 8 + j]);
            ss += hv * attSl[g * 8 + j];
            dd += hv * attDl[g * 8 + j];
        }
        if (node < NN) {
            a1s[(size_t)node * NH1 + g] = ss;
            a1d[(size_t)node * NH1 + g] = dd;
        }
    }
}

// ---------------- Fused layer-1 aggregation + layer-2 GEMM ----------------
// Block = 16 dst nodes (4 waves x 4 dsts, R12's measured-optimal agg loop
// verbatim). helu never leaves LDS: after __syncthreads the same block does
// h2 = helu @ W2 via MFMA (wave w = col-tile w) + a2s/a2d epilogue. Deletes
// the mgemm2 dispatch and 25.6 MB of helu round-trip traffic.
// hl stride 72 ch (144 B): A-frag ds_read_b128 lands 2-way-bank (free).

#define HLP 72

__global__ __launch_bounds__(256) void k_agg1f(
    const int* __restrict__ offs, const int* __restrict__ perm,
    const __hip_bfloat16* __restrict__ h1, const float* __restrict__ a1s,
    const float* __restrict__ a1d, const void* __restrict__ b1,
    const unsigned short* __restrict__ W2p,
    const void* __restrict__ attS2, const void* __restrict__ attD2,
    __hip_bfloat16* __restrict__ h2, float* __restrict__ a2s,
    float* __restrict__ a2d, int n, const int* __restrict__ flags) {
    int fp32 = flags[0];
    __shared__ unsigned short hl[16 * HLP];   // 2.25 KB helu tile (bf16 bits)
    __shared__ float attSl[64], attDl[64];
    __shared__ float sp[16 * 4], dp[16 * 4];
    int tid = threadIdx.x;
    if (tid < 64) { attSl[tid] = loadF(attS2, tid, fp32); attDl[tid] = loadF(attD2, tid, fp32); }
    int w = tid >> 6, c = tid & 63;
    int n0 = blockIdx.x * 16;
    int u = c & 7, h = c >> 3, cb = c & 56;
    const unsigned short* hu = (const unsigned short*)h1;

    // ---- phase 1: aggregation for this wave's 4 dsts (R12 loop, verbatim) ----
    for (int m = 0; m < 4; ++m) {
        int d = n0 + w * 4 + m;
        if (d < n) {
            int start = offs[d], end = offs[d + 1];
            float adl = a1d[(size_t)d * NH1 + h];
            float acc = 0.f, denp = 0.f;
            for (int i = start; i < end; i += 8) {
                int j = i + u;
                int jc = (j < end) ? j : (end - 1);
                int sj = perm[jc];
                float e = a1s[(size_t)sj * NH1 + h] + adl;
                e = fmaxf(e, 0.2f * e);                      // leaky_relu(0.2)
                float p = (j < end) ? __expf(e) : 0.f;
                denp += p;
                #pragma unroll
                for (int k = 0; k < 8; ++k) {
                    int su = __builtin_amdgcn_readlane(sj, k);   // wave-uniform src
                    float pk = __shfl(p, cb + k, 64);            // p(edge k, my head)
                    acc = fmaf(pk, b2f(hu[(size_t)su * 64 + c]), acc);
                }
            }
            denp += __shfl_xor(denp, 1, 64);
            denp += __shfl_xor(denp, 2, 64);
            denp += __shfl_xor(denp, 4, 64);                 // den for head c>>3
            float v = acc / (denp + 1e-16f) + loadF(b1, c, fp32);
            v = (v > 0.f) ? v : expm1f(v);                   // ELU
            hl[(w * 4 + m) * HLP + c] = f2bfu(v);
        }
    }
    __syncthreads();

    // ---- phase 2: h2 tile = hl @ W2 (wave w = col-tile w) ----
    int quad = c >> 4, lm = c & 15;
    bf16x8 bf0 = *(const bf16x8*)(W2p + (0 * 4 + w) * 512 + c * 8);
    bf16x8 bf1 = *(const bf16x8*)(W2p + (1 * 4 + w) * 512 + c * 8);
    bf16x8 af0 = *(const bf16x8*)(hl + lm * HLP + 0 * 32 + quad * 8);
    bf16x8 af1 = *(const bf16x8*)(hl + lm * HLP + 1 * 32 + quad * 8);
    f32x4 acc2 = (f32x4){0.f, 0.f, 0.f, 0.f};
    acc2 = __builtin_amdgcn_mfma_f32_16x16x32_bf16(af0, bf0, acc2, 0, 0, 0);
    acc2 = __builtin_amdgcn_mfma_f32_16x16x32_bf16(af1, bf1, acc2, 0, 0, 0);

    int cg = w * 16 + lm;                                // global output col
    float aSc = attSl[cg], aDc = attDl[cg];
    #pragma unroll
    for (int r = 0; r < 4; ++r) {
        int nl = quad * 4 + r;
        int node = n0 + nl;
        unsigned short hb = f2bfu(acc2[r]);
        if (node < n) ((unsigned short*)h2)[(size_t)node * 64 + cg] = hb;
        float hv = b2f(hb);
        float pvs = hv * aSc, pvd = hv * aDc;
        pvs += __shfl_xor(pvs, 1, 64); pvd += __shfl_xor(pvd, 1, 64);
        pvs += __shfl_xor(pvs, 2, 64); pvd += __shfl_xor(pvd, 2, 64);
        pvs += __shfl_xor(pvs, 4, 64); pvd += __shfl_xor(pvd, 4, 64);
        pvs += __shfl_xor(pvs, 8, 64); pvd += __shfl_xor(pvd, 8, 64);
        if (lm == 0) { sp[nl * 4 + w] = pvs; dp[nl * 4 + w] = pvd; }
    }
    __syncthreads();
    if (tid < 16) {
        int node = n0 + tid;
        if (node < n) {
            a2s[node] = sp[tid * 4 + 0] + sp[tid * 4 + 1] + sp[tid * 4 + 2] + sp[tid * 4 + 3];
            a2d[node] = dp[tid * 4 + 0] + dp[tid * 4 + 1] + dp[tid * 4 + 2] + dp[tid * 4 + 3];
        }
    }
}

// ---------------- Layer 2 aggregation + final linear (R9 exact) ----------------

__global__ __launch_bounds__(256) void k_agg2(
    const int* __restrict__ offs, const int* __restrict__ perm,
    const __hip_bfloat16* __restrict__ h2, const float* __restrict__ a2s,
    const float* __restrict__ a2d, const void* __restrict__ b2,
    const void* __restrict__ linW, const void* __restrict__ linb,
    void* __restrict__ out, int n, const int* __restrict__ flags) {
    int fp32 = flags[0];
    int w = threadIdx.x >> 6, c = threadIdx.x & 63;
    int d = blockIdx.x * 4 + w;
    if (d >= n) return;
    int start = offs[d], end = offs[d + 1];
    int u = c & 7;
    float ad = a2d[d];
    const unsigned short* hu = (const unsigned short*)h2;
    float acc = 0.f, denp = 0.f;
    for (int i = start; i < end; i += 8) {
        int j = i + u;
        int jc = (j < end) ? j : (end - 1);
        int sj = perm[jc];
        float e = a2s[sj] + ad;
        e = fmaxf(e, 0.2f * e);
        float p = (j < end) ? __expf(e) : 0.f;
        denp += (c < 8) ? p : 0.f;                   // dedup (p duplicated across groups)
        #pragma unroll
        for (int k = 0; k < 8; ++k) {
            int su = __builtin_amdgcn_readlane(sj, k);
            float pk = __uint_as_float(__builtin_amdgcn_readlane(__float_as_uint(p), k));
            acc = fmaf(pk, b2f(hu[(size_t)su * 64 + c]), acc);
        }
    }
    #pragma unroll
    for (int off = 1; off < 64; off <<= 1) denp += __shfl_xor(denp, off, 64);
    float v = acc / (denp + 1e-16f) + loadF(b2, c, fp32);
    float part = v * loadF(linW, c, fp32);
    #pragma unroll
    for (int off = 1; off < 64; off <<= 1) part += __shfl_xor(part, off, 64);
    if (c == 0) {
        float r = part + loadF(linb, 0, fp32);
        if (fp32) ((float*)out)[d] = r;
        else      ((__hip_bfloat16*)out)[d] = __float2bfloat16(r);
    }
}

// ---------------- host launcher ----------------

static inline char* carve(char*& p, size_t bytes) {
    char* r = p;
    p += (bytes + 255) & ~size_t(255);
    return r;
}

extern "C" void kernel_launch(void* const* d_in, const int* in_sizes, int n_in,
                              void* d_out, int out_size, void* d_ws, size_t ws_size,
                              hipStream_t stream) {
    const void* x     = d_in[0];
    const void* ei    = d_in[1];
    const void* W1    = d_in[2];
    const void* attS1 = d_in[3];
    const void* attD1 = d_in[4];
    const void* b1    = d_in[5];
    const void* W2    = d_in[6];
    const void* attS2 = d_in[7];
    const void* attD2 = d_in[8];
    const void* b2    = d_in[9];
    const void* linW  = d_in[10];
    const void* linb  = d_in[11];

    int E    = in_sizes[1] / 2;
    int Etot = E + NN;

    // workspace layout (~23.5 MB)
    char* p = (char*)d_ws;
    int*   flags = (int*)carve(p, 256);
    int*   bcnt  = (int*)carve(p, (size_t)NB * 4);
    unsigned short* W1p = (unsigned short*)carve(p, 8192 * 2);
    unsigned short* W2p = (unsigned short*)carve(p, 4096 * 2);
    int*   offs  = (int*)carve(p, (size_t)(NN + 1) * 4);       // 200 KB
    int*   perm  = (int*)carve(p, (size_t)Etot * 4);           // 6.6 MB
    // big region: binned (7.43 MB) dead after k_csr_local, then aliased by
    // a1s (1.6) + a1d (1.6) + h1 (6.4) written by k_mgemm1 afterwards.
    char*  big   = carve(p, 9600000);
    unsigned* binned = (unsigned*)big;
    float*    a1s    = (float*)big;
    float*    a1d    = (float*)(big + 1600000);
    __hip_bfloat16* h1 = (__hip_bfloat16*)(big + 3200000);
    // fused agg1 writes h2/a2s/a2d while other blocks still read h1/a1s/a1d
    // -> MUST be separate storage (no aliasing like the unfused version had).
    __hip_bfloat16* h2  = (__hip_bfloat16*)carve(p, (size_t)NN * F2 * 2);  // 6.4 MB
    float* a2s = (float*)carve(p, (size_t)NN * 4);             // 200 KB
    float* a2d = (float*)carve(p, (size_t)NN * 4);             // 200 KB

    k_pre<<<PREB, 256, 0, stream>>>(x, ei, flags, W1, W2, W1p, W2p, bcnt);

    int ab = (Etot + 2047) / 2048;
    k_bin_fine<<<ab, 256, 0, stream>>>(ei, E, Etot, bcnt, binned, flags);
    k_csr_local<<<NB, 256, 0, stream>>>(bcnt, binned, offs, perm);

    int ng = (NN + 63) / 64;
    k_mgemm1<<<ng, 256, 0, stream>>>(x, W1p, attS1, attD1, h1, a1s, a1d, flags);
    k_agg1f<<<(NN + 15) / 16, 256, 0, stream>>>(offs, perm, h1, a1s, a1d, b1,
                                                W2p, attS2, attD2, h2, a2s, a2d, NN, flags);
    k_agg2<<<(NN + 3) / 4, 256, 0, stream>>>(offs, perm, h2, a2s, a2d, b2, linW, linb, d_out, NN, flags);
}

// Round 14
// 232.819 us; speedup vs baseline: 1.2118x; 1.0808x over previous
//
#include <hip/hip_runtime.h>
#include <hip/hip_bf16.h>
#include <math.h>

#define NN     50000
#define FIN    128
#define F1     64      // H1*C1 = layer-1 output features
#define NH1    8
#define F2     64      // layer-2 output features

#define BSH    256                         // nodes per dst bucket (CSR build)
#define NB     ((NN + BSH - 1) / BSH)      // 196 buckets
#define BCAP   9472                        // per-bucket edge cap (mean 8448, +11 sigma)

typedef __bf16 bf16x8 __attribute__((ext_vector_type(8)));
typedef float  f32x4  __attribute__((ext_vector_type(4)));

// ---------------- runtime dtype helpers ----------------
// flags[0] = 1 if float tensors are fp32 (else bf16)
// flags[1] = 1 if edge_index is int64 (else int32)

__device__ __forceinline__ float loadF(const void* p, long long i, int fp32) {
    if (fp32) return ((const float*)p)[i];
    return __bfloat162float(((const __hip_bfloat16*)p)[i]);
}
__device__ __forceinline__ int loadI_nt(const void* p, long long i, int i64) {
    if (i64) return (int)__builtin_nontemporal_load(&((const long long*)p)[i]);
    return __builtin_nontemporal_load(&((const int*)p)[i]);
}
__device__ __forceinline__ unsigned short f2bfu(float f) {   // RNE f32->bf16 bits
    unsigned u = __float_as_uint(f);
    return (unsigned short)((u + 0x7FFFu + ((u >> 16) & 1u)) >> 16);
}
__device__ __forceinline__ float b2f(unsigned short u) {
    return __uint_as_float(((unsigned)u) << 16);
}

// ---------------- sniff + weight pre-swizzle (multi-block) + bcnt zero ----------------

#define PREB 49

__global__ __launch_bounds__(256) void k_pre(
    const void* __restrict__ x, const void* __restrict__ ei,
    int* __restrict__ flags,
    const void* __restrict__ W1, const void* __restrict__ W2,
    unsigned short* __restrict__ W1p, unsigned short* __restrict__ W2p,
    int* __restrict__ bcnt) {
    __shared__ int s_nanexp, s_oddnz, s_fp32;
    if (threadIdx.x == 0) { s_nanexp = 0; s_oddnz = 0; }
    if (blockIdx.x == 0 && threadIdx.x < NB) bcnt[threadIdx.x] = 0;   // folded memset
    __syncthreads();
    const unsigned short* u = (const unsigned short*)x;
    int cnt = 0;
    for (int i = threadIdx.x; i < 8192; i += 256) {
        unsigned short v = u[i];
        if ((v & 0x7F80) == 0x7F80) cnt++;         // bf16 Inf/NaN bit pattern
    }
    if (cnt) atomicAdd(&s_nanexp, cnt);
    const unsigned* e32 = (const unsigned*)ei;
    int nz = 0;
    for (int i = threadIdx.x; i < 2048; i += 256) {
        if (e32[2 * i + 1] != 0u) nz++;            // high words if int64
    }
    if (nz) atomicAdd(&s_oddnz, nz);
    __syncthreads();
    if (threadIdx.x == 0) {
        s_fp32 = (s_nanexp > 2) ? 1 : 0;
        if (blockIdx.x == 0) {
            flags[0] = s_fp32;
            flags[1] = (s_oddnz == 0) ? 1 : 0;
        }
    }
    __syncthreads();
    int fp32 = s_fp32;
    int gt = blockIdx.x * 256 + threadIdx.x, gs = PREB * 256;
    for (int i = gt; i < (FIN / 32) * 4 * 512; i += gs) {   // 8192
        int j = i & 7, l = (i >> 3) & 63, f = i >> 9;
        int kb = f >> 2, nt = f & 3;
        int k = kb * 32 + (l >> 4) * 8 + j, n = nt * 16 + (l & 15);
        W1p[i] = f2bfu(loadF(W1, k * 64 + n, fp32));
    }
    for (int i = gt; i < (F1 / 32) * 4 * 512; i += gs) {    // 4096
        int j = i & 7, l = (i >> 3) & 63, f = i >> 9;
        int kb = f >> 2, nt = f & 3;
        int k = kb * 32 + (l >> 4) * 8 + j, n = nt * 16 + (l & 15);
        W2p[i] = f2bfu(loadF(W2, k * 64 + n, fp32));
    }
}

// ---------------- CSR build: bucket bin + per-block LDS counting sort ----
// R13 accounting put bin+csr at ~40us each (hidden below top-5). Both were
// parallelism-starved: csr_local ran 196 blocks x 4 waves (<1 block/CU);
// bin_fine's 2048-edge blocks wrote 10-edge (40B) runs per bucket. Now both
// use 1024-thread blocks: 16 waves of latency hiding, and bin_fine's 8192-edge
// blocks write 42-edge (168B) runs.

__global__ __launch_bounds__(1024) void k_bin_fine(
    const void* __restrict__ ei, int E, int Etot,
    int* __restrict__ bcnt, unsigned* __restrict__ binned,
    const int* __restrict__ flags) {
    int i64 = flags[1];
    __shared__ int hist[NB], gbase[NB];
    for (int i = threadIdx.x; i < NB; i += 1024) hist[i] = 0;
    __syncthreads();
    long long base = (long long)blockIdx.x * 8192;
    unsigned pk[8]; short bb[8];
    #pragma unroll
    for (int u = 0; u < 8; ++u) {
        long long j = base + u * 1024 + threadIdx.x;
        int s = -1, d = -1;
        if (j < Etot) {
            if (j < E) { s = loadI_nt(ei, j, i64); d = loadI_nt(ei, (long long)E + j, i64); }
            else       { s = d = (int)(j - E); }
        }
        if ((unsigned)s < NN && (unsigned)d < NN) {
            bb[u] = (short)(d >> 8);
            pk[u] = ((unsigned)s << 8) | (unsigned)(d & 255);
            atomicAdd(&hist[bb[u]], 1);
        } else bb[u] = -1;
    }
    __syncthreads();
    for (int i = threadIdx.x; i < NB; i += 1024) {
        int h = hist[i];
        gbase[i] = h ? atomicAdd(&bcnt[i], h) : 0;
        hist[i] = 0;                                 // reuse as local cursor
    }
    __syncthreads();
    #pragma unroll
    for (int u = 0; u < 8; ++u) {
        if (bb[u] >= 0) {
            int pos = gbase[bb[u]] + atomicAdd(&hist[bb[u]], 1);
            if (pos < BCAP) binned[(size_t)bb[u] * BCAP + pos] = pk[u];
        }
    }
}

__global__ __launch_bounds__(1024) void k_csr_local(
    const int* __restrict__ bcnt, const unsigned* __restrict__ binned,
    int* __restrict__ offs, int* __restrict__ perm) {
    __shared__ int hist[BSH], cur[BSH], sd[BSH];
    int bk = blockIdx.x, tid = threadIdx.x;
    int n0 = bk * BSH;
    // phase 0: prefix over the 196 bucket counts (first 256 threads compute;
    // barriers are block-uniform)
    if (tid < 256) sd[tid] = (tid < NB) ? min(bcnt[tid], BCAP) : 0;
    __syncthreads();
    for (int off = 1; off < BSH; off <<= 1) {
        int t = 0;
        if (tid < 256 && tid >= off) t = sd[tid - off];
        __syncthreads();
        if (tid < 256) sd[tid] += t;
        __syncthreads();
    }
    int gb = (bk > 0) ? sd[bk - 1] : 0;
    if (bk == 0 && tid == 0) offs[NN] = sd[NB - 1];
    __syncthreads();
    // phase 1: histogram of dst&255 within bucket
    int cnt = bcnt[bk]; if (cnt > BCAP) cnt = BCAP;
    const unsigned* bp = binned + (size_t)bk * BCAP;
    if (tid < 256) hist[tid] = 0;
    __syncthreads();
    for (int i = tid; i < cnt; i += 1024)
        atomicAdd(&hist[bp[i] & 255], 1);
    __syncthreads();
    int myh = (tid < 256) ? hist[tid] : 0;
    if (tid < 256) sd[tid] = myh;
    __syncthreads();
    for (int off = 1; off < BSH; off <<= 1) {
        int t = 0;
        if (tid < 256 && tid >= off) t = sd[tid - off];
        __syncthreads();
        if (tid < 256) sd[tid] += t;
        __syncthreads();
    }
    if (tid < 256) {
        int excl = sd[tid] - myh;
        cur[tid] = gb + excl;
        if (n0 + tid < NN) offs[n0 + tid] = gb + excl;
    }
    __syncthreads();
    for (int i = tid; i < cnt; i += 1024) {
        unsigned pk = bp[i];
        int pos = atomicAdd(&cur[pk & 255], 1);
        perm[pos] = (int)(pk >> 8);
    }
}

// ---------------- MFMA GEMM (layer 1): h1 = x @ W1, + a1s/a1d (R9 exact) ----------------

__global__ __launch_bounds__(256) void k_mgemm1(
    const void* __restrict__ x, const unsigned short* __restrict__ W1p,
    const void* __restrict__ attS, const void* __restrict__ attD,
    __hip_bfloat16* __restrict__ h1, float* __restrict__ a1s,
    float* __restrict__ a1d, const int* __restrict__ flags) {
    int fp32 = flags[0];
    __shared__ unsigned short hl[64 * 64];   // 8 KB, bf16 bits
    __shared__ float attSl[64], attDl[64];
    int tid = threadIdx.x;
    if (tid < 64) { attSl[tid] = loadF(attS, tid, fp32); attDl[tid] = loadF(attD, tid, fp32); }
    int w = tid >> 6, l = tid & 63;
    int quad = l >> 4, lm = l & 15;
    int n0 = blockIdx.x * 64;

    bf16x8 bfr[16];
    #pragma unroll
    for (int f = 0; f < 16; ++f)
        bfr[f] = *(const bf16x8*)(W1p + f * 512 + l * 8);

    int nodeA = n0 + w * 16 + lm;
    long long rowA = (nodeA < NN) ? nodeA : 0;     // clamp; garbage unused
    f32x4 acc[4];
    #pragma unroll
    for (int nt = 0; nt < 4; ++nt) acc[nt] = (f32x4){0.f, 0.f, 0.f, 0.f};

    #pragma unroll
    for (int kb = 0; kb < 4; ++kb) {
        bf16x8 af;
        if (!fp32) {
            af = *(const bf16x8*)((const unsigned short*)x + rowA * FIN + kb * 32 + quad * 8);
        } else {
            const float* xf = (const float*)x + rowA * FIN + kb * 32 + quad * 8;
            union { unsigned short s[8]; bf16x8 v; } tmp;
            #pragma unroll
            for (int j = 0; j < 8; ++j) tmp.s[j] = f2bfu(xf[j]);
            af = tmp.v;
        }
        #pragma unroll
        for (int nt = 0; nt < 4; ++nt)
            acc[nt] = __builtin_amdgcn_mfma_f32_16x16x32_bf16(af, bfr[kb * 4 + nt], acc[nt], 0, 0, 0);
    }

    #pragma unroll
    for (int nt = 0; nt < 4; ++nt) {
        #pragma unroll
        for (int r = 0; r < 4; ++r) {
            int nl = w * 16 + quad * 4 + r;
            int node = n0 + nl;
            int c = nt * 16 + lm;
            unsigned short hb = f2bfu(acc[nt][r]);
            hl[nl * 64 + c] = hb;
            if (node < NN) ((unsigned short*)h1)[(size_t)node * 64 + c] = hb;
        }
    }
    __syncthreads();
    // a1s/a1d per (node, head): 64 nodes x 8 heads = 512 pairs
    #pragma unroll
    for (int pp = 0; pp < 2; ++pp) {
        int p = tid + pp * 256;
        int nl = p >> 3, g = p & 7;
        int node = n0 + nl;
        float ss = 0.f, dd = 0.f;
        #pragma unroll
        for (int j = 0; j < 8; ++j) {
            float hv = b2f(hl[nl * 64 + g * 8 + j]);
            ss += hv * attSl[g * 8 + j];
            dd += hv * attDl[g * 8 + j];
        }
        if (node < NN) {
            a1s[(size_t)node * NH1 + g] = ss;
            a1d[(size_t)node * NH1 + g] = dd;
        }
    }
}

// ---------------- Fused layer-1 aggregation + layer-2 GEMM (R13) ----------------

#define HLP 72

__global__ __launch_bounds__(256) void k_agg1f(
    const int* __restrict__ offs, const int* __restrict__ perm,
    const __hip_bfloat16* __restrict__ h1, const float* __restrict__ a1s,
    const float* __restrict__ a1d, const void* __restrict__ b1,
    const unsigned short* __restrict__ W2p,
    const void* __restrict__ attS2, const void* __restrict__ attD2,
    __hip_bfloat16* __restrict__ h2, float* __restrict__ a2s,
    float* __restrict__ a2d, int n, const int* __restrict__ flags) {
    int fp32 = flags[0];
    __shared__ unsigned short hl[16 * HLP];   // 2.25 KB helu tile (bf16 bits)
    __shared__ float attSl[64], attDl[64];
    __shared__ float sp[16 * 4], dp[16 * 4];
    int tid = threadIdx.x;
    if (tid < 64) { attSl[tid] = loadF(attS2, tid, fp32); attDl[tid] = loadF(attD2, tid, fp32); }
    int w = tid >> 6, c = tid & 63;
    int n0 = blockIdx.x * 16;
    int u = c & 7, h = c >> 3, cb = c & 56;
    const unsigned short* hu = (const unsigned short*)h1;

    // ---- phase 1: aggregation for this wave's 4 dsts (R12 loop, verbatim) ----
    for (int m = 0; m < 4; ++m) {
        int d = n0 + w * 4 + m;
        if (d < n) {
            int start = offs[d], end = offs[d + 1];
            float adl = a1d[(size_t)d * NH1 + h];
            float acc = 0.f, denp = 0.f;
            for (int i = start; i < end; i += 8) {
                int j = i + u;
                int jc = (j < end) ? j : (end - 1);
                int sj = perm[jc];
                float e = a1s[(size_t)sj * NH1 + h] + adl;
                e = fmaxf(e, 0.2f * e);                      // leaky_relu(0.2)
                float p = (j < end) ? __expf(e) : 0.f;
                denp += p;
                #pragma unroll
                for (int k = 0; k < 8; ++k) {
                    int su = __builtin_amdgcn_readlane(sj, k);   // wave-uniform src
                    float pk = __shfl(p, cb + k, 64);            // p(edge k, my head)
                    acc = fmaf(pk, b2f(hu[(size_t)su * 64 + c]), acc);
                }
            }
            denp += __shfl_xor(denp, 1, 64);
            denp += __shfl_xor(denp, 2, 64);
            denp += __shfl_xor(denp, 4, 64);                 // den for head c>>3
            float v = acc / (denp + 1e-16f) + loadF(b1, c, fp32);
            v = (v > 0.f) ? v : expm1f(v);                   // ELU
            hl[(w * 4 + m) * HLP + c] = f2bfu(v);
        }
    }
    __syncthreads();

    // ---- phase 2: h2 tile = hl @ W2 (wave w = col-tile w) ----
    int quad = c >> 4, lm = c & 15;
    bf16x8 bf0 = *(const bf16x8*)(W2p + (0 * 4 + w) * 512 + c * 8);
    bf16x8 bf1 = *(const bf16x8*)(W2p + (1 * 4 + w) * 512 + c * 8);
    bf16x8 af0 = *(const bf16x8*)(hl + lm * HLP + 0 * 32 + quad * 8);
    bf16x8 af1 = *(const bf16x8*)(hl + lm * HLP + 1 * 32 + quad * 8);
    f32x4 acc2 = (f32x4){0.f, 0.f, 0.f, 0.f};
    acc2 = __builtin_amdgcn_mfma_f32_16x16x32_bf16(af0, bf0, acc2, 0, 0, 0);
    acc2 = __builtin_amdgcn_mfma_f32_16x16x32_bf16(af1, bf1, acc2, 0, 0, 0);

    int cg = w * 16 + lm;                                // global output col
    float aSc = attSl[cg], aDc = attDl[cg];
    #pragma unroll
    for (int r = 0; r < 4; ++r) {
        int nl = quad * 4 + r;
        int node = n0 + nl;
        unsigned short hb = f2bfu(acc2[r]);
        if (node < n) ((unsigned short*)h2)[(size_t)node * 64 + cg] = hb;
        float hv = b2f(hb);
        float pvs = hv * aSc, pvd = hv * aDc;
        pvs += __shfl_xor(pvs, 1, 64); pvd += __shfl_xor(pvd, 1, 64);
        pvs += __shfl_xor(pvs, 2, 64); pvd += __shfl_xor(pvd, 2, 64);
        pvs += __shfl_xor(pvs, 4, 64); pvd += __shfl_xor(pvd, 4, 64);
        pvs += __shfl_xor(pvs, 8, 64); pvd += __shfl_xor(pvd, 8, 64);
        if (lm == 0) { sp[nl * 4 + w] = pvs; dp[nl * 4 + w] = pvd; }
    }
    __syncthreads();
    if (tid < 16) {
        int node = n0 + tid;
        if (node < n) {
            a2s[node] = sp[tid * 4 + 0] + sp[tid * 4 + 1] + sp[tid * 4 + 2] + sp[tid * 4 + 3];
            a2d[node] = dp[tid * 4 + 0] + dp[tid * 4 + 1] + dp[tid * 4 + 2] + dp[tid * 4 + 3];
        }
    }
}

// ---------------- Layer 2 aggregation + final linear (R9 exact) ----------------

__global__ __launch_bounds__(256) void k_agg2(
    const int* __restrict__ offs, const int* __restrict__ perm,
    const __hip_bfloat16* __restrict__ h2, const float* __restrict__ a2s,
    const float* __restrict__ a2d, const void* __restrict__ b2,
    const void* __restrict__ linW, const void* __restrict__ linb,
    void* __restrict__ out, int n, const int* __restrict__ flags) {
    int fp32 = flags[0];
    int w = threadIdx.x >> 6, c = threadIdx.x & 63;
    int d = blockIdx.x * 4 + w;
    if (d >= n) return;
    int start = offs[d], end = offs[d + 1];
    int u = c & 7;
    float ad = a2d[d];
    const unsigned short* hu = (const unsigned short*)h2;
    float acc = 0.f, denp = 0.f;
    for (int i = start; i < end; i += 8) {
        int j = i + u;
        int jc = (j < end) ? j : (end - 1);
        int sj = perm[jc];
        float e = a2s[sj] + ad;
        e = fmaxf(e, 0.2f * e);
        float p = (j < end) ? __expf(e) : 0.f;
        denp += (c < 8) ? p : 0.f;                   // dedup (p duplicated across groups)
        #pragma unroll
        for (int k = 0; k < 8; ++k) {
            int su = __builtin_amdgcn_readlane(sj, k);
            float pk = __uint_as_float(__builtin_amdgcn_readlane(__float_as_uint(p), k));
            acc = fmaf(pk, b2f(hu[(size_t)su * 64 + c]), acc);
        }
    }
    #pragma unroll
    for (int off = 1; off < 64; off <<= 1) denp += __shfl_xor(denp, off, 64);
    float v = acc / (denp + 1e-16f) + loadF(b2, c, fp32);
    float part = v * loadF(linW, c, fp32);
    #pragma unroll
    for (int off = 1; off < 64; off <<= 1) part += __shfl_xor(part, off, 64);
    if (c == 0) {
        float r = part + loadF(linb, 0, fp32);
        if (fp32) ((float*)out)[d] = r;
        else      ((__hip_bfloat16*)out)[d] = __float2bfloat16(r);
    }
}

// ---------------- host launcher ----------------

static inline char* carve(char*& p, size_t bytes) {
    char* r = p;
    p += (bytes + 255) & ~size_t(255);
    return r;
}

extern "C" void kernel_launch(void* const* d_in, const int* in_sizes, int n_in,
                              void* d_out, int out_size, void* d_ws, size_t ws_size,
                              hipStream_t stream) {
    const void* x     = d_in[0];
    const void* ei    = d_in[1];
    const void* W1    = d_in[2];
    const void* attS1 = d_in[3];
    const void* attD1 = d_in[4];
    const void* b1    = d_in[5];
    const void* W2    = d_in[6];
    const void* attS2 = d_in[7];
    const void* attD2 = d_in[8];
    const void* b2    = d_in[9];
    const void* linW  = d_in[10];
    const void* linb  = d_in[11];

    int E    = in_sizes[1] / 2;
    int Etot = E + NN;

    // workspace layout (~23.5 MB)
    char* p = (char*)d_ws;
    int*   flags = (int*)carve(p, 256);
    int*   bcnt  = (int*)carve(p, (size_t)NB * 4);
    unsigned short* W1p = (unsigned short*)carve(p, 8192 * 2);
    unsigned short* W2p = (unsigned short*)carve(p, 4096 * 2);
    int*   offs  = (int*)carve(p, (size_t)(NN + 1) * 4);       // 200 KB
    int*   perm  = (int*)carve(p, (size_t)Etot * 4);           // 6.6 MB
    // big region: binned (7.43 MB) dead after k_csr_local, then aliased by
    // a1s (1.6) + a1d (1.6) + h1 (6.4) written by k_mgemm1 afterwards.
    char*  big   = carve(p, 9600000);
    unsigned* binned = (unsigned*)big;
    float*    a1s    = (float*)big;
    float*    a1d    = (float*)(big + 1600000);
    __hip_bfloat16* h1 = (__hip_bfloat16*)(big + 3200000);
    // fused agg1 writes h2/a2s/a2d while other blocks still read h1/a1s/a1d
    // -> MUST be separate storage.
    __hip_bfloat16* h2  = (__hip_bfloat16*)carve(p, (size_t)NN * F2 * 2);  // 6.4 MB
    float* a2s = (float*)carve(p, (size_t)NN * 4);             // 200 KB
    float* a2d = (float*)carve(p, (size_t)NN * 4);             // 200 KB

    k_pre<<<PREB, 256, 0, stream>>>(x, ei, flags, W1, W2, W1p, W2p, bcnt);

    int ab = (Etot + 8191) / 8192;
    k_bin_fine<<<ab, 1024, 0, stream>>>(ei, E, Etot, bcnt, binned, flags);
    k_csr_local<<<NB, 1024, 0, stream>>>(bcnt, binned, offs, perm);

    int ng = (NN + 63) / 64;
    k_mgemm1<<<ng, 256, 0, stream>>>(x, W1p, attS1, attD1, h1, a1s, a1d, flags);
    k_agg1f<<<(NN + 15) / 16, 256, 0, stream>>>(offs, perm, h1, a1s, a1d, b1,
                                                W2p, attS2, attD2, h2, a2s, a2d, NN, flags);
    k_agg2<<<(NN + 3) / 4, 256, 0, stream>>>(offs, perm, h2, a2s, a2d, b2, linW, linb, d_out, NN, flags);
}

// Round 15
// 225.013 us; speedup vs baseline: 1.2539x; 1.0347x over previous
//
#include <hip/hip_runtime.h>
#include <hip/hip_bf16.h>
#include <math.h>

#define NN     50000
#define FIN    128
#define F1     64      // H1*C1 = layer-1 output features
#define NH1    8
#define F2     64      // layer-2 output features

#define BSH    256                         // nodes per dst bucket (CSR build)
#define NB     ((NN + BSH - 1) / BSH)      // 196 buckets
#define BCAP   9472                        // per-bucket edge cap (mean 8448, +11 sigma)
#define PREB   13                          // swizzle blocks in k_front
#define MG1B   ((NN + 255) / 256)          // 196 mgemm1 super-blocks in k_mid

typedef __bf16 bf16x8 __attribute__((ext_vector_type(8)));
typedef float  f32x4  __attribute__((ext_vector_type(4)));

// ---------------- runtime dtype helpers ----------------
// flags[0] = 1 if float tensors are fp32 (else bf16)
// flags[1] = 1 if edge_index is int64 (else int32)

__device__ __forceinline__ float loadF(const void* p, long long i, int fp32) {
    if (fp32) return ((const float*)p)[i];
    return __bfloat162float(((const __hip_bfloat16*)p)[i]);
}
__device__ __forceinline__ int loadI_nt(const void* p, long long i, int i64) {
    if (i64) return (int)__builtin_nontemporal_load(&((const long long*)p)[i]);
    return __builtin_nontemporal_load(&((const int*)p)[i]);
}
__device__ __forceinline__ unsigned short f2bfu(float f) {   // RNE f32->bf16 bits
    unsigned u = __float_as_uint(f);
    return (unsigned short)((u + 0x7FFFu + ((u >> 16) & 1u)) >> 16);
}
__device__ __forceinline__ float b2f(unsigned short u) {
    return __uint_as_float(((unsigned)u) << 16);
}

// ---------------- k_front: [sniff + W-swizzle] | [edge binning] ----------------
// Blocks 0..PREB-1: sniff dtypes (block 0 publishes flags) + swizzle W1p/W2p.
// Blocks PREB.. : bin 8192 edges each into 256-node dst buckets; each bin
// block sniffs edge int-width itself, so binning has NO dependency on the
// pre blocks and overlaps them on the machine.

__global__ __launch_bounds__(1024) void k_front(
    const void* __restrict__ x, const void* __restrict__ ei, int E, int Etot,
    int* __restrict__ flags,
    const void* __restrict__ W1, const void* __restrict__ W2,
    unsigned short* __restrict__ W1p, unsigned short* __restrict__ W2p,
    int* __restrict__ bcnt, unsigned* __restrict__ binned) {
    __shared__ int s_a, s_b;
    __shared__ int hist[NB], gbase[NB];
    int tid = threadIdx.x;
    if (blockIdx.x < PREB) {
        if (tid == 0) { s_a = 0; s_b = 0; }
        __syncthreads();
        const unsigned short* u = (const unsigned short*)x;
        int cnt = 0;
        for (int i = tid; i < 8192; i += 1024) {
            unsigned short v = u[i];
            if ((v & 0x7F80) == 0x7F80) cnt++;     // bf16 Inf/NaN pattern
        }
        if (cnt) atomicAdd(&s_a, cnt);
        const unsigned* e32 = (const unsigned*)ei;
        int nz = 0;
        for (int i = tid; i < 2048; i += 1024) {
            if (e32[2 * i + 1] != 0u) nz++;        // high words if int64
        }
        if (nz) atomicAdd(&s_b, nz);
        __syncthreads();
        int fp32 = (s_a > 2) ? 1 : 0;
        if (tid == 0 && blockIdx.x == 0) {
            flags[0] = fp32;
            flags[1] = (s_b == 0) ? 1 : 0;
        }
        int gt = blockIdx.x * 1024 + tid, gs = PREB * 1024;
        for (int i = gt; i < (FIN / 32) * 4 * 512; i += gs) {   // 8192
            int j = i & 7, l = (i >> 3) & 63, f = i >> 9;
            int kb = f >> 2, nt = f & 3;
            int k = kb * 32 + (l >> 4) * 8 + j, n = nt * 16 + (l & 15);
            W1p[i] = f2bfu(loadF(W1, k * 64 + n, fp32));
        }
        for (int i = gt; i < (F1 / 32) * 4 * 512; i += gs) {    // 4096
            int j = i & 7, l = (i >> 3) & 63, f = i >> 9;
            int kb = f >> 2, nt = f & 3;
            int k = kb * 32 + (l >> 4) * 8 + j, n = nt * 16 + (l & 15);
            W2p[i] = f2bfu(loadF(W2, k * 64 + n, fp32));
        }
    } else {
        // ---- bin role (own int-width sniff; R14 1024-thread bin body) ----
        if (tid == 0) s_b = 0;
        for (int i = tid; i < NB; i += 1024) hist[i] = 0;
        __syncthreads();
        const unsigned* e32 = (const unsigned*)ei;
        int nz = 0;
        for (int i = tid; i < 2048; i += 1024) {
            if (e32[2 * i + 1] != 0u) nz++;
        }
        if (nz) atomicAdd(&s_b, nz);
        __syncthreads();
        int i64 = (s_b == 0) ? 1 : 0;
        long long base = (long long)(blockIdx.x - PREB) * 8192;
        unsigned pk[8]; short bb[8];
        #pragma unroll
        for (int u = 0; u < 8; ++u) {
            long long j = base + u * 1024 + tid;
            int s = -1, d = -1;
            if (j < Etot) {
                if (j < E) { s = loadI_nt(ei, j, i64); d = loadI_nt(ei, (long long)E + j, i64); }
                else       { s = d = (int)(j - E); }
            }
            if ((unsigned)s < NN && (unsigned)d < NN) {
                bb[u] = (short)(d >> 8);
                pk[u] = ((unsigned)s << 8) | (unsigned)(d & 255);
                atomicAdd(&hist[bb[u]], 1);
            } else bb[u] = -1;
        }
        __syncthreads();
        for (int i = tid; i < NB; i += 1024) {
            int h = hist[i];
            gbase[i] = h ? atomicAdd(&bcnt[i], h) : 0;
            hist[i] = 0;                             // reuse as local cursor
        }
        __syncthreads();
        #pragma unroll
        for (int u = 0; u < 8; ++u) {
            if (bb[u] >= 0) {
                int pos = gbase[bb[u]] + atomicAdd(&hist[bb[u]], 1);
                if (pos < BCAP) binned[(size_t)bb[u] * BCAP + pos] = pk[u];
            }
        }
    }
}

// ---------------- k_mid: [CSR counting sort] | [layer-1 MFMA GEMM] ----------------
// Blocks 0..NB-1: csr_local (R14 verbatim). Blocks NB..NB+MG1B-1: mgemm1 as
// 4 x 256-thread sub-tiles (256 nodes/block). The latency-bound LDS sort
// overlaps the compute-bound GEMM. Shared-memory arena unions the two roles.

__global__ __launch_bounds__(1024) void k_mid(
    const int* __restrict__ bcnt, const unsigned* __restrict__ binned,
    int* __restrict__ offs, int* __restrict__ perm,
    const void* __restrict__ x, const unsigned short* __restrict__ W1p,
    const void* __restrict__ attS, const void* __restrict__ attD,
    __hip_bfloat16* __restrict__ h1, float* __restrict__ a1s,
    float* __restrict__ a1d, const int* __restrict__ flags) {
    __shared__ __align__(16) char smem[33280];     // max(csr 3KB, mgemm 33KB)
    int tid = threadIdx.x;
    if (blockIdx.x < NB) {
        int* hist = (int*)smem;
        int* cur  = (int*)(smem + 1024);
        int* sd   = (int*)(smem + 2048);
        int bk = blockIdx.x;
        int n0 = bk * BSH;
        if (tid < 256) sd[tid] = (tid < NB) ? min(bcnt[tid], BCAP) : 0;
        __syncthreads();
        for (int off = 1; off < BSH; off <<= 1) {
            int t = 0;
            if (tid < 256 && tid >= off) t = sd[tid - off];
            __syncthreads();
            if (tid < 256) sd[tid] += t;
            __syncthreads();
        }
        int gb = (bk > 0) ? sd[bk - 1] : 0;
        if (bk == 0 && tid == 0) offs[NN] = sd[NB - 1];
        __syncthreads();
        int cnt = bcnt[bk]; if (cnt > BCAP) cnt = BCAP;
        const unsigned* bp = binned + (size_t)bk * BCAP;
        if (tid < 256) hist[tid] = 0;
        __syncthreads();
        for (int i = tid; i < cnt; i += 1024)
            atomicAdd(&hist[bp[i] & 255], 1);
        __syncthreads();
        int myh = (tid < 256) ? hist[tid] : 0;
        if (tid < 256) sd[tid] = myh;
        __syncthreads();
        for (int off = 1; off < BSH; off <<= 1) {
            int t = 0;
            if (tid < 256 && tid >= off) t = sd[tid - off];
            __syncthreads();
            if (tid < 256) sd[tid] += t;
            __syncthreads();
        }
        if (tid < 256) {
            int excl = sd[tid] - myh;
            cur[tid] = gb + excl;
            if (n0 + tid < NN) offs[n0 + tid] = gb + excl;
        }
        __syncthreads();
        for (int i = tid; i < cnt; i += 1024) {
            unsigned pk = bp[i];
            int pos = atomicAdd(&cur[pk & 255], 1);
            perm[pos] = (int)(pk >> 8);
        }
    } else {
        // ---- mgemm1 role: 4 sub-tiles of 64 nodes ----
        int fp32 = flags[0];
        unsigned short* hl = (unsigned short*)smem;          // 4 x 4096 ushort
        float* attSl = (float*)(smem + 32768);
        float* attDl = (float*)(smem + 32768 + 256);
        if (tid < 64) { attSl[tid] = loadF(attS, tid, fp32); attDl[tid] = loadF(attD, tid, fp32); }
        int sub = tid >> 8, t = tid & 255;
        int w = t >> 6, l = t & 63;
        int quad = l >> 4, lm = l & 15;
        int n0 = (blockIdx.x - NB) * 256 + sub * 64;
        unsigned short* hls = hl + sub * 4096;

        bf16x8 bfr[16];
        #pragma unroll
        for (int f = 0; f < 16; ++f)
            bfr[f] = *(const bf16x8*)(W1p + f * 512 + l * 8);

        int nodeA = n0 + w * 16 + lm;
        long long rowA = (nodeA < NN) ? nodeA : 0;     // clamp; garbage unused
        f32x4 acc[4];
        #pragma unroll
        for (int nt = 0; nt < 4; ++nt) acc[nt] = (f32x4){0.f, 0.f, 0.f, 0.f};

        #pragma unroll
        for (int kb = 0; kb < 4; ++kb) {
            bf16x8 af;
            if (!fp32) {
                af = *(const bf16x8*)((const unsigned short*)x + rowA * FIN + kb * 32 + quad * 8);
            } else {
                const float* xf = (const float*)x + rowA * FIN + kb * 32 + quad * 8;
                union { unsigned short s[8]; bf16x8 v; } tmp;
                #pragma unroll
                for (int j = 0; j < 8; ++j) tmp.s[j] = f2bfu(xf[j]);
                af = tmp.v;
            }
            #pragma unroll
            for (int nt = 0; nt < 4; ++nt)
                acc[nt] = __builtin_amdgcn_mfma_f32_16x16x32_bf16(af, bfr[kb * 4 + nt], acc[nt], 0, 0, 0);
        }

        #pragma unroll
        for (int nt = 0; nt < 4; ++nt) {
            #pragma unroll
            for (int r = 0; r < 4; ++r) {
                int nl = w * 16 + quad * 4 + r;
                int node = n0 + nl;
                int c = nt * 16 + lm;
                unsigned short hb = f2bfu(acc[nt][r]);
                hls[nl * 64 + c] = hb;
                if (node < NN) ((unsigned short*)h1)[(size_t)node * 64 + c] = hb;
            }
        }
        __syncthreads();
        // a1s/a1d per (node, head): 64 nodes x 8 heads = 512 pairs per sub
        #pragma unroll
        for (int pp = 0; pp < 2; ++pp) {
            int p = t + pp * 256;
            int nl = p >> 3, g = p & 7;
            int node = n0 + nl;
            float ss = 0.f, dd = 0.f;
            #pragma unroll
            for (int j = 0; j < 8; ++j) {
                float hv = b2f(hls[nl * 64 + g * 8 + j]);
                ss += hv * attSl[g * 8 + j];
                dd += hv * attDl[g * 8 + j];
            }
            if (node < NN) {
                a1s[(size_t)node * NH1 + g] = ss;
                a1d[(size_t)node * NH1 + g] = dd;
            }
        }
    }
}

// ---------------- Fused layer-1 aggregation + layer-2 GEMM (R13/R14 verbatim) ----------------

#define HLP 72

__global__ __launch_bounds__(256) void k_agg1f(
    const int* __restrict__ offs, const int* __restrict__ perm,
    const __hip_bfloat16* __restrict__ h1, const float* __restrict__ a1s,
    const float* __restrict__ a1d, const void* __restrict__ b1,
    const unsigned short* __restrict__ W2p,
    const void* __restrict__ attS2, const void* __restrict__ attD2,
    __hip_bfloat16* __restrict__ h2, float* __restrict__ a2s,
    float* __restrict__ a2d, int n, const int* __restrict__ flags) {
    int fp32 = flags[0];
    __shared__ unsigned short hl[16 * HLP];   // 2.25 KB helu tile (bf16 bits)
    __shared__ float attSl[64], attDl[64];
    __shared__ float sp[16 * 4], dp[16 * 4];
    int tid = threadIdx.x;
    if (tid < 64) { attSl[tid] = loadF(attS2, tid, fp32); attDl[tid] = loadF(attD2, tid, fp32); }
    int w = tid >> 6, c = tid & 63;
    int n0 = blockIdx.x * 16;
    int u = c & 7, h = c >> 3, cb = c & 56;
    const unsigned short* hu = (const unsigned short*)h1;

    // ---- phase 1: aggregation for this wave's 4 dsts (R12 loop, verbatim) ----
    for (int m = 0; m < 4; ++m) {
        int d = n0 + w * 4 + m;
        if (d < n) {
            int start = offs[d], end = offs[d + 1];
            float adl = a1d[(size_t)d * NH1 + h];
            float acc = 0.f, denp = 0.f;
            for (int i = start; i < end; i += 8) {
                int j = i + u;
                int jc = (j < end) ? j : (end - 1);
                int sj = perm[jc];
                float e = a1s[(size_t)sj * NH1 + h] + adl;
                e = fmaxf(e, 0.2f * e);                      // leaky_relu(0.2)
                float p = (j < end) ? __expf(e) : 0.f;
                denp += p;
                #pragma unroll
                for (int k = 0; k < 8; ++k) {
                    int su = __builtin_amdgcn_readlane(sj, k);   // wave-uniform src
                    float pk = __shfl(p, cb + k, 64);            // p(edge k, my head)
                    acc = fmaf(pk, b2f(hu[(size_t)su * 64 + c]), acc);
                }
            }
            denp += __shfl_xor(denp, 1, 64);
            denp += __shfl_xor(denp, 2, 64);
            denp += __shfl_xor(denp, 4, 64);                 // den for head c>>3
            float v = acc / (denp + 1e-16f) + loadF(b1, c, fp32);
            v = (v > 0.f) ? v : expm1f(v);                   // ELU
            hl[(w * 4 + m) * HLP + c] = f2bfu(v);
        }
    }
    __syncthreads();

    // ---- phase 2: h2 tile = hl @ W2 (wave w = col-tile w) ----
    int quad = c >> 4, lm = c & 15;
    bf16x8 bf0 = *(const bf16x8*)(W2p + (0 * 4 + w) * 512 + c * 8);
    bf16x8 bf1 = *(const bf16x8*)(W2p + (1 * 4 + w) * 512 + c * 8);
    bf16x8 af0 = *(const bf16x8*)(hl + lm * HLP + 0 * 32 + quad * 8);
    bf16x8 af1 = *(const bf16x8*)(hl + lm * HLP + 1 * 32 + quad * 8);
    f32x4 acc2 = (f32x4){0.f, 0.f, 0.f, 0.f};
    acc2 = __builtin_amdgcn_mfma_f32_16x16x32_bf16(af0, bf0, acc2, 0, 0, 0);
    acc2 = __builtin_amdgcn_mfma_f32_16x16x32_bf16(af1, bf1, acc2, 0, 0, 0);

    int cg = w * 16 + lm;                                // global output col
    float aSc = attSl[cg], aDc = attDl[cg];
    #pragma unroll
    for (int r = 0; r < 4; ++r) {
        int nl = quad * 4 + r;
        int node = n0 + nl;
        unsigned short hb = f2bfu(acc2[r]);
        if (node < n) ((unsigned short*)h2)[(size_t)node * 64 + cg] = hb;
        float hv = b2f(hb);
        float pvs = hv * aSc, pvd = hv * aDc;
        pvs += __shfl_xor(pvs, 1, 64); pvd += __shfl_xor(pvd, 1, 64);
        pvs += __shfl_xor(pvs, 2, 64); pvd += __shfl_xor(pvd, 2, 64);
        pvs += __shfl_xor(pvs, 4, 64); pvd += __shfl_xor(pvd, 4, 64);
        pvs += __shfl_xor(pvs, 8, 64); pvd += __shfl_xor(pvd, 8, 64);
        if (lm == 0) { sp[nl * 4 + w] = pvs; dp[nl * 4 + w] = pvd; }
    }
    __syncthreads();
    if (tid < 16) {
        int node = n0 + tid;
        if (node < n) {
            a2s[node] = sp[tid * 4 + 0] + sp[tid * 4 + 1] + sp[tid * 4 + 2] + sp[tid * 4 + 3];
            a2d[node] = dp[tid * 4 + 0] + dp[tid * 4 + 1] + dp[tid * 4 + 2] + dp[tid * 4 + 3];
        }
    }
}

// ---------------- Layer 2 aggregation + final linear (R9 exact) ----------------

__global__ __launch_bounds__(256) void k_agg2(
    const int* __restrict__ offs, const int* __restrict__ perm,
    const __hip_bfloat16* __restrict__ h2, const float* __restrict__ a2s,
    const float* __restrict__ a2d, const void* __restrict__ b2,
    const void* __restrict__ linW, const void* __restrict__ linb,
    void* __restrict__ out, int n, const int* __restrict__ flags) {
    int fp32 = flags[0];
    int w = threadIdx.x >> 6, c = threadIdx.x & 63;
    int d = blockIdx.x * 4 + w;
    if (d >= n) return;
    int start = offs[d], end = offs[d + 1];
    int u = c & 7;
    float ad = a2d[d];
    const unsigned short* hu = (const unsigned short*)h2;
    float acc = 0.f, denp = 0.f;
    for (int i = start; i < end; i += 8) {
        int j = i + u;
        int jc = (j < end) ? j : (end - 1);
        int sj = perm[jc];
        float e = a2s[sj] + ad;
        e = fmaxf(e, 0.2f * e);
        float p = (j < end) ? __expf(e) : 0.f;
        denp += (c < 8) ? p : 0.f;                   // dedup (p duplicated across groups)
        #pragma unroll
        for (int k = 0; k < 8; ++k) {
            int su = __builtin_amdgcn_readlane(sj, k);
            float pk = __uint_as_float(__builtin_amdgcn_readlane(__float_as_uint(p), k));
            acc = fmaf(pk, b2f(hu[(size_t)su * 64 + c]), acc);
        }
    }
    #pragma unroll
    for (int off = 1; off < 64; off <<= 1) denp += __shfl_xor(denp, off, 64);
    float v = acc / (denp + 1e-16f) + loadF(b2, c, fp32);
    float part = v * loadF(linW, c, fp32);
    #pragma unroll
    for (int off = 1; off < 64; off <<= 1) part += __shfl_xor(part, off, 64);
    if (c == 0) {
        float r = part + loadF(linb, 0, fp32);
        if (fp32) ((float*)out)[d] = r;
        else      ((__hip_bfloat16*)out)[d] = __float2bfloat16(r);
    }
}

// ---------------- host launcher ----------------

static inline char* carve(char*& p, size_t bytes) {
    char* r = p;
    p += (bytes + 255) & ~size_t(255);
    return r;
}

extern "C" void kernel_launch(void* const* d_in, const int* in_sizes, int n_in,
                              void* d_out, int out_size, void* d_ws, size_t ws_size,
                              hipStream_t stream) {
    const void* x     = d_in[0];
    const void* ei    = d_in[1];
    const void* W1    = d_in[2];
    const void* attS1 = d_in[3];
    const void* attD1 = d_in[4];
    const void* b1    = d_in[5];
    const void* W2    = d_in[6];
    const void* attS2 = d_in[7];
    const void* attD2 = d_in[8];
    const void* b2    = d_in[9];
    const void* linW  = d_in[10];
    const void* linb  = d_in[11];

    int E    = in_sizes[1] / 2;
    int Etot = E + NN;

    // workspace layout (~23.5 MB)
    char* p = (char*)d_ws;
    int*   flags = (int*)carve(p, 256);
    int*   bcnt  = (int*)carve(p, (size_t)NB * 4);
    unsigned short* W1p = (unsigned short*)carve(p, 8192 * 2);
    unsigned short* W2p = (unsigned short*)carve(p, 4096 * 2);
    int*   offs  = (int*)carve(p, (size_t)(NN + 1) * 4);       // 200 KB
    int*   perm  = (int*)carve(p, (size_t)Etot * 4);           // 6.6 MB
    // big region: binned (7.43 MB) dead after k_mid's csr role, then aliased
    // by a1s (1.6) + a1d (1.6) + h1 (6.4) written by k_mid's mgemm role.
    // NOTE: csr blocks and mgemm blocks run concurrently in k_mid, but csr
    // only READS binned and mgemm only WRITES a1s/a1d/h1 — overlap is safe
    // ONLY because those regions are disjoint in this layout:
    //   binned occupies [0, 7.43MB) and is fully consumed by csr;
    //   a1s/a1d/h1 writes land in [0, 9.6MB) — OVERLAP! Fix: give binned its
    //   own region this round (workspace grows to ~31 MB, still fine).
    unsigned* binned = (unsigned*)carve(p, (size_t)NB * BCAP * 4);  // 7.43 MB
    float*    a1s    = (float*)carve(p, (size_t)NN * NH1 * 4);      // 1.6 MB
    float*    a1d    = (float*)carve(p, (size_t)NN * NH1 * 4);      // 1.6 MB
    __hip_bfloat16* h1 = (__hip_bfloat16*)carve(p, (size_t)NN * F1 * 2);  // 6.4 MB
    __hip_bfloat16* h2 = (__hip_bfloat16*)carve(p, (size_t)NN * F2 * 2);  // 6.4 MB
    float* a2s = (float*)carve(p, (size_t)NN * 4);             // 200 KB
    float* a2d = (float*)carve(p, (size_t)NN * 4);             // 200 KB

    hipMemsetAsync(bcnt, 0, (size_t)NB * 4, stream);

    int nbin = (Etot + 8191) / 8192;
    k_front<<<PREB + nbin, 1024, 0, stream>>>(x, ei, E, Etot, flags,
                                              W1, W2, W1p, W2p, bcnt, binned);
    k_mid<<<NB + MG1B, 1024, 0, stream>>>(bcnt, binned, offs, perm,
                                          x, W1p, attS1, attD1, h1, a1s, a1d, flags);
    k_agg1f<<<(NN + 15) / 16, 256, 0, stream>>>(offs, perm, h1, a1s, a1d, b1,
                                                W2p, attS2, attD2, h2, a2s, a2d, NN, flags);
    k_agg2<<<(NN + 3) / 4, 256, 0, stream>>>(offs, perm, h2, a2s, a2d, b2, linW, linb, d_out, NN, flags);
}

// Round 16
// 202.986 us; speedup vs baseline: 1.3899x; 1.1085x over previous
//
#include <hip/hip_runtime.h>
#include <hip/hip_bf16.h>
#include <math.h>

#define NN     50000
#define FIN    128
#define F1     64      // H1*C1 = layer-1 output features
#define NH1    8
#define F2     64      // layer-2 output features

#define BSH    256                         // nodes per dst bucket (CSR build)
#define NB     ((NN + BSH - 1) / BSH)      // 196 buckets
#define BCAP   9472                        // per-bucket edge cap (mean 8448, +11 sigma)
#define PREB   13                          // swizzle blocks in k_front
#define MG1B   ((NN + 255) / 256)          // 196 mgemm1 super-blocks in k_mid

typedef __bf16 bf16x8 __attribute__((ext_vector_type(8)));
typedef float  f32x4  __attribute__((ext_vector_type(4)));

// ---------------- runtime dtype helpers ----------------
// flags[0] = 1 if float tensors are fp32 (else bf16)
// flags[1] = 1 if edge_index is int64 (else int32)

__device__ __forceinline__ float loadF(const void* p, long long i, int fp32) {
    if (fp32) return ((const float*)p)[i];
    return __bfloat162float(((const __hip_bfloat16*)p)[i]);
}
__device__ __forceinline__ int loadI_nt(const void* p, long long i, int i64) {
    if (i64) return (int)__builtin_nontemporal_load(&((const long long*)p)[i]);
    return __builtin_nontemporal_load(&((const int*)p)[i]);
}
__device__ __forceinline__ unsigned short f2bfu(float f) {   // RNE f32->bf16 bits
    unsigned u = __float_as_uint(f);
    return (unsigned short)((u + 0x7FFFu + ((u >> 16) & 1u)) >> 16);
}
__device__ __forceinline__ float b2f(unsigned short u) {
    return __uint_as_float(((unsigned)u) << 16);
}

// ---------------- k_front: [sniff + W-swizzle] | [edge binning] (R15) ----------------

__global__ __launch_bounds__(1024) void k_front(
    const void* __restrict__ x, const void* __restrict__ ei, int E, int Etot,
    int* __restrict__ flags,
    const void* __restrict__ W1, const void* __restrict__ W2,
    unsigned short* __restrict__ W1p, unsigned short* __restrict__ W2p,
    int* __restrict__ bcnt, unsigned* __restrict__ binned) {
    __shared__ int s_a, s_b;
    __shared__ int hist[NB], gbase[NB];
    int tid = threadIdx.x;
    if (blockIdx.x < PREB) {
        if (tid == 0) { s_a = 0; s_b = 0; }
        __syncthreads();
        const unsigned short* u = (const unsigned short*)x;
        int cnt = 0;
        for (int i = tid; i < 8192; i += 1024) {
            unsigned short v = u[i];
            if ((v & 0x7F80) == 0x7F80) cnt++;     // bf16 Inf/NaN pattern
        }
        if (cnt) atomicAdd(&s_a, cnt);
        const unsigned* e32 = (const unsigned*)ei;
        int nz = 0;
        for (int i = tid; i < 2048; i += 1024) {
            if (e32[2 * i + 1] != 0u) nz++;        // high words if int64
        }
        if (nz) atomicAdd(&s_b, nz);
        __syncthreads();
        int fp32 = (s_a > 2) ? 1 : 0;
        if (tid == 0 && blockIdx.x == 0) {
            flags[0] = fp32;
            flags[1] = (s_b == 0) ? 1 : 0;
        }
        int gt = blockIdx.x * 1024 + tid, gs = PREB * 1024;
        for (int i = gt; i < (FIN / 32) * 4 * 512; i += gs) {   // 8192
            int j = i & 7, l = (i >> 3) & 63, f = i >> 9;
            int kb = f >> 2, nt = f & 3;
            int k = kb * 32 + (l >> 4) * 8 + j, n = nt * 16 + (l & 15);
            W1p[i] = f2bfu(loadF(W1, k * 64 + n, fp32));
        }
        for (int i = gt; i < (F1 / 32) * 4 * 512; i += gs) {    // 4096
            int j = i & 7, l = (i >> 3) & 63, f = i >> 9;
            int kb = f >> 2, nt = f & 3;
            int k = kb * 32 + (l >> 4) * 8 + j, n = nt * 16 + (l & 15);
            W2p[i] = f2bfu(loadF(W2, k * 64 + n, fp32));
        }
    } else {
        // ---- bin role (own int-width sniff) ----
        if (tid == 0) s_b = 0;
        for (int i = tid; i < NB; i += 1024) hist[i] = 0;
        __syncthreads();
        const unsigned* e32 = (const unsigned*)ei;
        int nz = 0;
        for (int i = tid; i < 2048; i += 1024) {
            if (e32[2 * i + 1] != 0u) nz++;
        }
        if (nz) atomicAdd(&s_b, nz);
        __syncthreads();
        int i64 = (s_b == 0) ? 1 : 0;
        long long base = (long long)(blockIdx.x - PREB) * 8192;
        unsigned pk[8]; short bb[8];
        #pragma unroll
        for (int u = 0; u < 8; ++u) {
            long long j = base + u * 1024 + tid;
            int s = -1, d = -1;
            if (j < Etot) {
                if (j < E) { s = loadI_nt(ei, j, i64); d = loadI_nt(ei, (long long)E + j, i64); }
                else       { s = d = (int)(j - E); }
            }
            if ((unsigned)s < NN && (unsigned)d < NN) {
                bb[u] = (short)(d >> 8);
                pk[u] = ((unsigned)s << 8) | (unsigned)(d & 255);
                atomicAdd(&hist[bb[u]], 1);
            } else bb[u] = -1;
        }
        __syncthreads();
        for (int i = tid; i < NB; i += 1024) {
            int h = hist[i];
            gbase[i] = h ? atomicAdd(&bcnt[i], h) : 0;
            hist[i] = 0;                             // reuse as local cursor
        }
        __syncthreads();
        #pragma unroll
        for (int u = 0; u < 8; ++u) {
            if (bb[u] >= 0) {
                int pos = gbase[bb[u]] + atomicAdd(&hist[bb[u]], 1);
                if (pos < BCAP) binned[(size_t)bb[u] * BCAP + pos] = pk[u];
            }
        }
    }
}

// ---------------- k_mid: [CSR counting sort] | [layer-1 MFMA GEMM] (R15) ----------------

__global__ __launch_bounds__(1024) void k_mid(
    const int* __restrict__ bcnt, const unsigned* __restrict__ binned,
    int* __restrict__ offs, int* __restrict__ perm,
    const void* __restrict__ x, const unsigned short* __restrict__ W1p,
    const void* __restrict__ attS, const void* __restrict__ attD,
    __hip_bfloat16* __restrict__ h1, float* __restrict__ a1s,
    float* __restrict__ a1d, const int* __restrict__ flags) {
    __shared__ __align__(16) char smem[33280];     // max(csr 3KB, mgemm 33KB)
    int tid = threadIdx.x;
    if (blockIdx.x < NB) {
        int* hist = (int*)smem;
        int* cur  = (int*)(smem + 1024);
        int* sd   = (int*)(smem + 2048);
        int bk = blockIdx.x;
        int n0 = bk * BSH;
        if (tid < 256) sd[tid] = (tid < NB) ? min(bcnt[tid], BCAP) : 0;
        __syncthreads();
        for (int off = 1; off < BSH; off <<= 1) {
            int t = 0;
            if (tid < 256 && tid >= off) t = sd[tid - off];
            __syncthreads();
            if (tid < 256) sd[tid] += t;
            __syncthreads();
        }
        int gb = (bk > 0) ? sd[bk - 1] : 0;
        if (bk == 0 && tid == 0) offs[NN] = sd[NB - 1];
        __syncthreads();
        int cnt = bcnt[bk]; if (cnt > BCAP) cnt = BCAP;
        const unsigned* bp = binned + (size_t)bk * BCAP;
        if (tid < 256) hist[tid] = 0;
        __syncthreads();
        for (int i = tid; i < cnt; i += 1024)
            atomicAdd(&hist[bp[i] & 255], 1);
        __syncthreads();
        int myh = (tid < 256) ? hist[tid] : 0;
        if (tid < 256) sd[tid] = myh;
        __syncthreads();
        for (int off = 1; off < BSH; off <<= 1) {
            int t = 0;
            if (tid < 256 && tid >= off) t = sd[tid - off];
            __syncthreads();
            if (tid < 256) sd[tid] += t;
            __syncthreads();
        }
        if (tid < 256) {
            int excl = sd[tid] - myh;
            cur[tid] = gb + excl;
            if (n0 + tid < NN) offs[n0 + tid] = gb + excl;
        }
        __syncthreads();
        for (int i = tid; i < cnt; i += 1024) {
            unsigned pk = bp[i];
            int pos = atomicAdd(&cur[pk & 255], 1);
            perm[pos] = (int)(pk >> 8);
        }
    } else {
        // ---- mgemm1 role: 4 sub-tiles of 64 nodes ----
        int fp32 = flags[0];
        unsigned short* hl = (unsigned short*)smem;          // 4 x 4096 ushort
        float* attSl = (float*)(smem + 32768);
        float* attDl = (float*)(smem + 32768 + 256);
        if (tid < 64) { attSl[tid] = loadF(attS, tid, fp32); attDl[tid] = loadF(attD, tid, fp32); }
        int sub = tid >> 8, t = tid & 255;
        int w = t >> 6, l = t & 63;
        int quad = l >> 4, lm = l & 15;
        int n0 = (blockIdx.x - NB) * 256 + sub * 64;
        unsigned short* hls = hl + sub * 4096;

        bf16x8 bfr[16];
        #pragma unroll
        for (int f = 0; f < 16; ++f)
            bfr[f] = *(const bf16x8*)(W1p + f * 512 + l * 8);

        int nodeA = n0 + w * 16 + lm;
        long long rowA = (nodeA < NN) ? nodeA : 0;     // clamp; garbage unused
        f32x4 acc[4];
        #pragma unroll
        for (int nt = 0; nt < 4; ++nt) acc[nt] = (f32x4){0.f, 0.f, 0.f, 0.f};

        #pragma unroll
        for (int kb = 0; kb < 4; ++kb) {
            bf16x8 af;
            if (!fp32) {
                af = *(const bf16x8*)((const unsigned short*)x + rowA * FIN + kb * 32 + quad * 8);
            } else {
                const float* xf = (const float*)x + rowA * FIN + kb * 32 + quad * 8;
                union { unsigned short s[8]; bf16x8 v; } tmp;
                #pragma unroll
                for (int j = 0; j < 8; ++j) tmp.s[j] = f2bfu(xf[j]);
                af = tmp.v;
            }
            #pragma unroll
            for (int nt = 0; nt < 4; ++nt)
                acc[nt] = __builtin_amdgcn_mfma_f32_16x16x32_bf16(af, bfr[kb * 4 + nt], acc[nt], 0, 0, 0);
        }

        #pragma unroll
        for (int nt = 0; nt < 4; ++nt) {
            #pragma unroll
            for (int r = 0; r < 4; ++r) {
                int nl = w * 16 + quad * 4 + r;
                int node = n0 + nl;
                int c = nt * 16 + lm;
                unsigned short hb = f2bfu(acc[nt][r]);
                hls[nl * 64 + c] = hb;
                if (node < NN) ((unsigned short*)h1)[(size_t)node * 64 + c] = hb;
            }
        }
        __syncthreads();
        // a1s/a1d per (node, head): 64 nodes x 8 heads = 512 pairs per sub
        #pragma unroll
        for (int pp = 0; pp < 2; ++pp) {
            int p = t + pp * 256;
            int nl = p >> 3, g = p & 7;
            int node = n0 + nl;
            float ss = 0.f, dd = 0.f;
            #pragma unroll
            for (int j = 0; j < 8; ++j) {
                float hv = b2f(hls[nl * 64 + g * 8 + j]);
                ss += hv * attSl[g * 8 + j];
                dd += hv * attDl[g * 8 + j];
            }
            if (node < NN) {
                a1s[(size_t)node * NH1 + g] = ss;
                a1d[(size_t)node * NH1 + g] = dd;
            }
        }
    }
}

// ---------------- Fused layer-1 agg + layer-2 GEMM + scalar projection ----------------
// R16: layer-2 output feeds ONLY the final linear, so instead of storing h2
// we store g2[node] = h2[node]·linW (scalar) packed with a2s as float2.
// agg2's 128B/edge row gather becomes an 8B/edge scalar gather, and the
// 6.4 MB h2 global write disappears. Agg loop untouched (R12 optimum).

#define HLP 72

__global__ __launch_bounds__(256) void k_agg1f(
    const int* __restrict__ offs, const int* __restrict__ perm,
    const __hip_bfloat16* __restrict__ h1, const float* __restrict__ a1s,
    const float* __restrict__ a1d, const void* __restrict__ b1,
    const unsigned short* __restrict__ W2p,
    const void* __restrict__ attS2, const void* __restrict__ attD2,
    const void* __restrict__ linW,
    float2* __restrict__ g2s, float* __restrict__ a2d,
    int n, const int* __restrict__ flags) {
    int fp32 = flags[0];
    __shared__ unsigned short hl[16 * HLP];   // 2.25 KB helu tile (bf16 bits)
    __shared__ float attSl[64], attDl[64];
    __shared__ float sp[16 * 4], dp[16 * 4], gp[16 * 4];
    int tid = threadIdx.x;
    if (tid < 64) { attSl[tid] = loadF(attS2, tid, fp32); attDl[tid] = loadF(attD2, tid, fp32); }
    int w = tid >> 6, c = tid & 63;
    int n0 = blockIdx.x * 16;
    int u = c & 7, h = c >> 3, cb = c & 56;
    const unsigned short* hu = (const unsigned short*)h1;

    // ---- phase 1: aggregation for this wave's 4 dsts (R12 loop, verbatim) ----
    for (int m = 0; m < 4; ++m) {
        int d = n0 + w * 4 + m;
        if (d < n) {
            int start = offs[d], end = offs[d + 1];
            float adl = a1d[(size_t)d * NH1 + h];
            float acc = 0.f, denp = 0.f;
            for (int i = start; i < end; i += 8) {
                int j = i + u;
                int jc = (j < end) ? j : (end - 1);
                int sj = perm[jc];
                float e = a1s[(size_t)sj * NH1 + h] + adl;
                e = fmaxf(e, 0.2f * e);                      // leaky_relu(0.2)
                float p = (j < end) ? __expf(e) : 0.f;
                denp += p;
                #pragma unroll
                for (int k = 0; k < 8; ++k) {
                    int su = __builtin_amdgcn_readlane(sj, k);   // wave-uniform src
                    float pk = __shfl(p, cb + k, 64);            // p(edge k, my head)
                    acc = fmaf(pk, b2f(hu[(size_t)su * 64 + c]), acc);
                }
            }
            denp += __shfl_xor(denp, 1, 64);
            denp += __shfl_xor(denp, 2, 64);
            denp += __shfl_xor(denp, 4, 64);                 // den for head c>>3
            float v = acc / (denp + 1e-16f) + loadF(b1, c, fp32);
            v = (v > 0.f) ? v : expm1f(v);                   // ELU
            hl[(w * 4 + m) * HLP + c] = f2bfu(v);
        }
    }
    __syncthreads();

    // ---- phase 2: h2 tile = hl @ W2 (wave w = col-tile w); g2/a2s/a2d epilogue ----
    int quad = c >> 4, lm = c & 15;
    bf16x8 bf0 = *(const bf16x8*)(W2p + (0 * 4 + w) * 512 + c * 8);
    bf16x8 bf1 = *(const bf16x8*)(W2p + (1 * 4 + w) * 512 + c * 8);
    bf16x8 af0 = *(const bf16x8*)(hl + lm * HLP + 0 * 32 + quad * 8);
    bf16x8 af1 = *(const bf16x8*)(hl + lm * HLP + 1 * 32 + quad * 8);
    f32x4 acc2 = (f32x4){0.f, 0.f, 0.f, 0.f};
    acc2 = __builtin_amdgcn_mfma_f32_16x16x32_bf16(af0, bf0, acc2, 0, 0, 0);
    acc2 = __builtin_amdgcn_mfma_f32_16x16x32_bf16(af1, bf1, acc2, 0, 0, 0);

    int cg = w * 16 + lm;                                // global output col
    float aSc = attSl[cg], aDc = attDl[cg];
    float lWc = loadF(linW, cg, fp32);
    #pragma unroll
    for (int r = 0; r < 4; ++r) {
        int nl = quad * 4 + r;
        unsigned short hb = f2bfu(acc2[r]);              // same rounding as before
        float hv = b2f(hb);
        float pvs = hv * aSc, pvd = hv * aDc, pvg = hv * lWc;
        pvs += __shfl_xor(pvs, 1, 64); pvd += __shfl_xor(pvd, 1, 64); pvg += __shfl_xor(pvg, 1, 64);
        pvs += __shfl_xor(pvs, 2, 64); pvd += __shfl_xor(pvd, 2, 64); pvg += __shfl_xor(pvg, 2, 64);
        pvs += __shfl_xor(pvs, 4, 64); pvd += __shfl_xor(pvd, 4, 64); pvg += __shfl_xor(pvg, 4, 64);
        pvs += __shfl_xor(pvs, 8, 64); pvd += __shfl_xor(pvd, 8, 64); pvg += __shfl_xor(pvg, 8, 64);
        if (lm == 0) { sp[nl * 4 + w] = pvs; dp[nl * 4 + w] = pvd; gp[nl * 4 + w] = pvg; }
    }
    __syncthreads();
    if (tid < 16) {
        int node = n0 + tid;
        if (node < n) {
            float ss = sp[tid * 4 + 0] + sp[tid * 4 + 1] + sp[tid * 4 + 2] + sp[tid * 4 + 3];
            float dd = dp[tid * 4 + 0] + dp[tid * 4 + 1] + dp[tid * 4 + 2] + dp[tid * 4 + 3];
            float gg = gp[tid * 4 + 0] + gp[tid * 4 + 1] + gp[tid * 4 + 2] + gp[tid * 4 + 3];
            g2s[node] = make_float2(ss, gg);
            a2d[node] = dd;
        }
    }
}

// ---------------- Layer 2 aggregation, scalar form ----------------
// out[d] = sum_e p_e * g2[s_e] / den + (b2·linW + linb). Per edge: one perm
// read + one 8B gather + ~6 VALU; lanes work disjoint edges.

__global__ __launch_bounds__(256) void k_agg2(
    const int* __restrict__ offs, const int* __restrict__ perm,
    const float2* __restrict__ g2s, const float* __restrict__ a2d,
    const void* __restrict__ b2, const void* __restrict__ linW,
    const void* __restrict__ linb,
    void* __restrict__ out, int n, const int* __restrict__ flags) {
    int fp32 = flags[0];
    int w = threadIdx.x >> 6, c = threadIdx.x & 63;
    int d = blockIdx.x * 4 + w;
    if (d >= n) return;
    int start = offs[d], end = offs[d + 1];
    float ad = a2d[d];
    float acc = 0.f, den = 0.f;
    for (int i = start + c; i < end; i += 64) {
        int s = perm[i];
        float2 ag = g2s[s];
        float e = ag.x + ad;
        e = fmaxf(e, 0.2f * e);                      // leaky_relu(0.2)
        float p = __expf(e);
        acc = fmaf(p, ag.y, acc);
        den += p;
    }
    float cst = loadF(b2, c, fp32) * loadF(linW, c, fp32);   // b2·linW partial
    #pragma unroll
    for (int off = 1; off < 64; off <<= 1) {
        acc += __shfl_xor(acc, off, 64);
        den += __shfl_xor(den, off, 64);
        cst += __shfl_xor(cst, off, 64);
    }
    if (c == 0) {
        float r = acc / (den + 1e-16f) + cst + loadF(linb, 0, fp32);
        if (fp32) ((float*)out)[d] = r;
        else      ((__hip_bfloat16*)out)[d] = __float2bfloat16(r);
    }
}

// ---------------- host launcher ----------------

static inline char* carve(char*& p, size_t bytes) {
    char* r = p;
    p += (bytes + 255) & ~size_t(255);
    return r;
}

extern "C" void kernel_launch(void* const* d_in, const int* in_sizes, int n_in,
                              void* d_out, int out_size, void* d_ws, size_t ws_size,
                              hipStream_t stream) {
    const void* x     = d_in[0];
    const void* ei    = d_in[1];
    const void* W1    = d_in[2];
    const void* attS1 = d_in[3];
    const void* attD1 = d_in[4];
    const void* b1    = d_in[5];
    const void* W2    = d_in[6];
    const void* attS2 = d_in[7];
    const void* attD2 = d_in[8];
    const void* b2    = d_in[9];
    const void* linW  = d_in[10];
    const void* linb  = d_in[11];

    int E    = in_sizes[1] / 2;
    int Etot = E + NN;

    // workspace layout (~25 MB)
    char* p = (char*)d_ws;
    int*   flags = (int*)carve(p, 256);
    int*   bcnt  = (int*)carve(p, (size_t)NB * 4);
    unsigned short* W1p = (unsigned short*)carve(p, 8192 * 2);
    unsigned short* W2p = (unsigned short*)carve(p, 4096 * 2);
    int*   offs  = (int*)carve(p, (size_t)(NN + 1) * 4);       // 200 KB
    int*   perm  = (int*)carve(p, (size_t)Etot * 4);           // 6.6 MB
    // binned has its own region (k_mid overlaps csr reads with mgemm writes)
    unsigned* binned = (unsigned*)carve(p, (size_t)NB * BCAP * 4);  // 7.43 MB
    float*    a1s    = (float*)carve(p, (size_t)NN * NH1 * 4);      // 1.6 MB
    float*    a1d    = (float*)carve(p, (size_t)NN * NH1 * 4);      // 1.6 MB
    __hip_bfloat16* h1 = (__hip_bfloat16*)carve(p, (size_t)NN * F1 * 2);  // 6.4 MB
    float2* g2s = (float2*)carve(p, (size_t)NN * 8);           // 400 KB (a2s, g2)
    float*  a2d = (float*)carve(p, (size_t)NN * 4);            // 200 KB

    hipMemsetAsync(bcnt, 0, (size_t)NB * 4, stream);

    int nbin = (Etot + 8191) / 8192;
    k_front<<<PREB + nbin, 1024, 0, stream>>>(x, ei, E, Etot, flags,
                                              W1, W2, W1p, W2p, bcnt, binned);
    k_mid<<<NB + MG1B, 1024, 0, stream>>>(bcnt, binned, offs, perm,
                                          x, W1p, attS1, attD1, h1, a1s, a1d, flags);
    k_agg1f<<<(NN + 15) / 16, 256, 0, stream>>>(offs, perm, h1, a1s, a1d, b1,
                                                W2p, attS2, attD2, linW, g2s, a2d, NN, flags);
    k_agg2<<<(NN + 3) / 4, 256, 0, stream>>>(offs, perm, g2s, a2d, b2, linW, linb, d_out, NN, flags);
}